// Round 1
// baseline (1283.644 us; speedup 1.0000x reference)
//
#include <hip/hip_runtime.h>
#include <math.h>

// ---------------------------------------------------------------------------
// SplineCNN (ShapeNet part-seg) forward. fp32 throughout.
// Levels: N1=10000/E1=60000, N2=2500/E2=15000, N3=625/E3=3750, N4=160/E4=960
// ---------------------------------------------------------------------------

static const int N1 = 10000, E1 = 60000;
static const int N2 = 2500,  E2 = 15000;
static const int N3 = 625,   E3 = 3750;
static const int N4 = 160,   E4 = 960;
static const int NC = 4;

__device__ __forceinline__ float eluf(float x) { return x > 0.f ? x : expm1f(x); }

// ---------------------------------------------------------------------------
// Edge kernel: msg[e,o] = sum_{8 corners} wgt_c * (x[src] . W[idx_c][:,o])
// atomically accumulated into agg[dst,o]; deg[dst] += 1.
// Block = 256 threads; COUT lanes per edge -> 256/COUT edges per block.
// ---------------------------------------------------------------------------
template<int CIN, int COUT>
__global__ void spline_edge(const float* __restrict__ x, const int* __restrict__ ei,
                            const float* __restrict__ u, const float* __restrict__ W,
                            float* __restrict__ agg, float* __restrict__ deg, int E) {
    constexpr int EPB = 256 / COUT;
    const int lane = threadIdx.x % COUT;
    const int grp  = threadIdx.x / COUT;
    const int e = blockIdx.x * EPB + grp;
    if (e >= E) return;
    const int src = ei[e];
    const int dst = ei[E + e];
    float fr[3];
    int k0 = 0;
    #pragma unroll
    for (int d = 0; d < 3; ++d) {
        float v = u[e * 3 + d] * 4.0f;              // u * (K-1)
        float kf = floorf(v);
        kf = fminf(fmaxf(kf, 0.f), 3.f);            // clip to [0, K-2]
        fr[d] = v - kf;
        k0 = k0 * 5 + (int)kf;
    }
    const float* xs = x + (size_t)src * CIN;
    float acc = 0.f;
    #pragma unroll
    for (int c = 0; c < 8; ++c) {
        const int b0 = (c >> 2) & 1, b1 = (c >> 1) & 1, b2 = c & 1;
        const int idx = k0 + b0 * 25 + b1 * 5 + b2;
        const float wgt = (b0 ? fr[0] : 1.f - fr[0]) *
                          (b1 ? fr[1] : 1.f - fr[1]) *
                          (b2 ? fr[2] : 1.f - fr[2]);
        const float* Wk = W + (size_t)idx * (CIN * COUT) + lane;
        float s = 0.f;
        #pragma unroll 4
        for (int i = 0; i < CIN; ++i) s += xs[i] * Wk[i * COUT];
        acc += wgt * s;
    }
    atomicAdd(&agg[(size_t)dst * COUT + lane], acc);
    if (lane == 0) atomicAdd(&deg[dst], 1.0f);
}

// out[n,o] = elu( agg[n,o]/max(deg,1) + x[n,:] . R[:,o] + b[o] )
template<int CIN, int COUT>
__global__ void spline_node(const float* __restrict__ x, const float* __restrict__ agg,
                            const float* __restrict__ deg, const float* __restrict__ R,
                            const float* __restrict__ b, float* __restrict__ out, int N) {
    constexpr int NPB = 256 / COUT;
    const int lane = threadIdx.x % COUT;
    const int grp  = threadIdx.x / COUT;
    const int n = blockIdx.x * NPB + grp;
    if (n >= N) return;
    const float d = fmaxf(deg[n], 1.f);
    float s = agg[(size_t)n * COUT + lane] / d + b[lane];
    const float* xs = x + (size_t)n * CIN;
    #pragma unroll 4
    for (int i = 0; i < CIN; ++i) s += xs[i] * R[i * COUT + lane];
    out[(size_t)n * COUT + lane] = eluf(s);
}

// pool buffer [M, C+1]: cols 0..C-1 = -inf (atomic-max identity), col C = 1.0
__global__ void fill_pool(float* __restrict__ p, int M, int C) {
    const int t = blockIdx.x * 256 + threadIdx.x;
    const int total = M * (C + 1);
    if (t >= total) return;
    p[t] = (t % (C + 1) == C) ? 1.0f : -INFINITY;
}

// segment max: pool[cl[n], c] = max over n (sign-split atomic trick)
__global__ void segmax(const float* __restrict__ h, const int* __restrict__ cl,
                       float* __restrict__ pool, int N, int C, int STRIDE) {
    const int t = blockIdx.x * 256 + threadIdx.x;
    if (t >= N * C) return;
    const int n = t / C, c = t - n * C;
    const float v = h[t];
    float* addr = pool + (size_t)cl[n] * STRIDE + c;
    if (v >= 0.f) atomicMax((int*)addr, __float_as_int(v));
    else          atomicMin((unsigned int*)addr, __float_as_uint(v));
}

// out[n,o] = up[cl[n],o] + h[n,:64] . skw[:,o] + skb[o]   (no activation)
__global__ void skip_gather(const float* __restrict__ up, const int* __restrict__ cl,
                            const float* __restrict__ h, const float* __restrict__ skw,
                            const float* __restrict__ skb, float* __restrict__ out, int N) {
    const int lane = threadIdx.x & 31;
    const int grp  = threadIdx.x >> 5;
    const int n = blockIdx.x * 8 + grp;
    if (n >= N) return;
    float s = up[(size_t)cl[n] * 32 + lane] + skb[lane];
    const float* hs = h + (size_t)n * 64;
    #pragma unroll 4
    for (int i = 0; i < 64; ++i) s += hs[i] * skw[i * 32 + lane];
    out[(size_t)n * 32 + lane] = s;
}

// out[n,o] = elu( x[n,:64] . w[:,o] + b[o] )   (fc1)
__global__ void linear_elu_64_32(const float* __restrict__ x, const float* __restrict__ w,
                                 const float* __restrict__ b, float* __restrict__ out, int N) {
    const int lane = threadIdx.x & 31;
    const int grp  = threadIdx.x >> 5;
    const int n = blockIdx.x * 8 + grp;
    if (n >= N) return;
    float s = b[lane];
    const float* xs = x + (size_t)n * 64;
    #pragma unroll 4
    for (int i = 0; i < 64; ++i) s += xs[i] * w[i * 32 + lane];
    out[(size_t)n * 32 + lane] = eluf(s);
}

// logits = g1 @ fc2w + fc2b ; out = log_softmax(logits)
__global__ void final_logsoftmax(const float* __restrict__ g1, const float* __restrict__ w,
                                 const float* __restrict__ b, float* __restrict__ out, int N) {
    const int n = blockIdx.x * 256 + threadIdx.x;
    if (n >= N) return;
    const float* xs = g1 + (size_t)n * 32;
    float v[NC];
    #pragma unroll
    for (int o = 0; o < NC; ++o) {
        float s = b[o];
        #pragma unroll
        for (int i = 0; i < 32; ++i) s += xs[i] * w[i * NC + o];
        v[o] = s;
    }
    float m = fmaxf(fmaxf(v[0], v[1]), fmaxf(v[2], v[3]));
    float se = 0.f;
    #pragma unroll
    for (int o = 0; o < NC; ++o) se += expf(v[o] - m);
    const float l = logf(se);
    #pragma unroll
    for (int o = 0; o < NC; ++o) out[(size_t)n * NC + o] = v[o] - m - l;
}

// ---------------------------------------------------------------------------
// Host orchestration
// ---------------------------------------------------------------------------
template<int CIN, int COUT>
static void run_conv(hipStream_t s, const float* x, const int* ei, const float* u, int E,
                     const float* W, const float* R, const float* b, int N,
                     float* out, float* agg, float* deg) {
    (void)hipMemsetAsync(agg, 0, (size_t)N * COUT * sizeof(float), s);
    (void)hipMemsetAsync(deg, 0, (size_t)N * sizeof(float), s);
    constexpr int EPB = 256 / COUT;
    spline_edge<CIN, COUT><<<(E + EPB - 1) / EPB, 256, 0, s>>>(x, ei, u, W, agg, deg, E);
    constexpr int NPB = 256 / COUT;
    spline_node<CIN, COUT><<<(N + NPB - 1) / NPB, 256, 0, s>>>(x, agg, deg, R, b, out, N);
}

extern "C" void kernel_launch(void* const* d_in, const int* in_sizes, int n_in,
                              void* d_out, int out_size, void* d_ws, size_t ws_size,
                              hipStream_t stream) {
    // Inputs in setup_inputs() dict order:
    const float* x    = (const float*)d_in[0];
    const int*   ei1  = (const int*)  d_in[1];
    const float* u1   = (const float*)d_in[2];
    const int*   ei2  = (const int*)  d_in[3];
    const float* u2   = (const float*)d_in[4];
    const int*   ei3  = (const int*)  d_in[5];
    const float* u3   = (const float*)d_in[6];
    const int*   ei4  = (const int*)  d_in[7];
    const float* u4   = (const float*)d_in[8];
    const int*   c1   = (const int*)  d_in[9];
    const int*   c2   = (const int*)  d_in[10];
    const int*   c3   = (const int*)  d_in[11];
    const float *w1  = (const float*)d_in[12], *r1  = (const float*)d_in[13], *b1  = (const float*)d_in[14];
    const float *w12 = (const float*)d_in[15], *r12 = (const float*)d_in[16], *b12 = (const float*)d_in[17];
    const float *w2  = (const float*)d_in[18], *r2  = (const float*)d_in[19], *b2  = (const float*)d_in[20];
    const float *w22 = (const float*)d_in[21], *r22 = (const float*)d_in[22], *b22 = (const float*)d_in[23];
    const float *w3  = (const float*)d_in[24], *r3  = (const float*)d_in[25], *b3  = (const float*)d_in[26];
    const float *w32 = (const float*)d_in[27], *r32 = (const float*)d_in[28], *b32 = (const float*)d_in[29];
    const float *w4  = (const float*)d_in[30], *r4  = (const float*)d_in[31], *b4  = (const float*)d_in[32];
    const float *w42 = (const float*)d_in[33], *r42 = (const float*)d_in[34], *b42 = (const float*)d_in[35];
    const float *w5  = (const float*)d_in[36], *r5  = (const float*)d_in[37], *b5  = (const float*)d_in[38];
    const float *w6  = (const float*)d_in[39], *r6  = (const float*)d_in[40], *b6  = (const float*)d_in[41];
    const float *w7  = (const float*)d_in[42], *r7  = (const float*)d_in[43], *b7  = (const float*)d_in[44];
    const float *fc1w = (const float*)d_in[45], *fc1b = (const float*)d_in[46];
    const float *fc2w = (const float*)d_in[47], *fc2b = (const float*)d_in[48];
    const float *sk1w = (const float*)d_in[49], *sk1b = (const float*)d_in[50];
    const float *sk2w = (const float*)d_in[51], *sk2b = (const float*)d_in[52];
    const float *sk3w = (const float*)d_in[53], *sk3b = (const float*)d_in[54];
    float* out = (float*)d_out;

    // Workspace bump allocator (floats, 256B aligned)
    float* ws = (float*)d_ws;
    size_t off = 0;
    auto alloc = [&](size_t n) { float* p = ws + off; off += (n + 63) & ~(size_t)63; return p; };
    float* h1a  = alloc((size_t)N1 * 64);
    float* h1   = alloc((size_t)N1 * 64);
    float* h2in = alloc((size_t)N2 * 65);
    float* h2a  = alloc((size_t)N2 * 64);
    float* h2   = alloc((size_t)N2 * 64);
    float* h3in = alloc((size_t)N3 * 65);
    float* h3a  = alloc((size_t)N3 * 64);
    float* h3   = alloc((size_t)N3 * 64);
    float* h4in = alloc((size_t)N4 * 65);
    float* h4a  = alloc((size_t)N4 * 64);
    float* h4b  = alloc((size_t)N4 * 64);
    float* h4c  = alloc((size_t)N4 * 64);
    float* h4   = alloc((size_t)N4 * 32);
    float* g3in = alloc((size_t)N3 * 32);
    float* g3   = alloc((size_t)N3 * 32);
    float* g2in = alloc((size_t)N2 * 32);
    float* g2   = alloc((size_t)N2 * 32);
    float* g1in = alloc((size_t)N1 * 32);
    float* g1   = alloc((size_t)N1 * 32);
    float* agg  = alloc((size_t)N1 * 64);
    float* deg  = alloc((size_t)N1);

    // ---- Level 1 ----
    run_conv<1, 64>(stream, x,   ei1, u1, E1, w1,  r1,  b1,  N1, h1a, agg, deg);
    run_conv<64, 64>(stream, h1a, ei1, u1, E1, w12, r12, b12, N1, h1,  agg, deg);

    // pool 1 -> h2in [N2, 65]
    fill_pool<<<(N2 * 65 + 255) / 256, 256, 0, stream>>>(h2in, N2, 64);
    segmax<<<(N1 * 64 + 255) / 256, 256, 0, stream>>>(h1, c1, h2in, N1, 64, 65);

    // ---- Level 2 ----
    run_conv<65, 64>(stream, h2in, ei2, u2, E2, w2,  r2,  b2,  N2, h2a, agg, deg);
    run_conv<64, 64>(stream, h2a,  ei2, u2, E2, w22, r22, b22, N2, h2,  agg, deg);

    // pool 2 -> h3in
    fill_pool<<<(N3 * 65 + 255) / 256, 256, 0, stream>>>(h3in, N3, 64);
    segmax<<<(N2 * 64 + 255) / 256, 256, 0, stream>>>(h2, c2, h3in, N2, 64, 65);

    // ---- Level 3 ----
    run_conv<65, 64>(stream, h3in, ei3, u3, E3, w3,  r3,  b3,  N3, h3a, agg, deg);
    run_conv<64, 64>(stream, h3a,  ei3, u3, E3, w32, r32, b32, N3, h3,  agg, deg);

    // pool 3 -> h4in
    fill_pool<<<(N4 * 65 + 255) / 256, 256, 0, stream>>>(h4in, N4, 64);
    segmax<<<(N3 * 64 + 255) / 256, 256, 0, stream>>>(h3, c3, h4in, N3, 64, 65);

    // ---- Level 4 ----
    run_conv<65, 64>(stream, h4in, ei4, u4, E4, w4,  r4,  b4,  N4, h4a, agg, deg);
    run_conv<64, 64>(stream, h4a,  ei4, u4, E4, w42, r42, b42, N4, h4b, agg, deg);
    run_conv<64, 64>(stream, h4b,  ei4, u4, E4, w42, r42, b42, N4, h4c, agg, deg); // applied twice

    // fc1 + elu -> h4 [N4, 32]
    linear_elu_64_32<<<(N4 + 7) / 8, 256, 0, stream>>>(h4c, fc1w, fc1b, h4, N4);

    // ---- Decoder ----
    skip_gather<<<(N3 + 7) / 8, 256, 0, stream>>>(h4, c3, h3, sk3w, sk3b, g3in, N3);
    run_conv<32, 32>(stream, g3in, ei3, u3, E3, w5, r5, b5, N3, g3, agg, deg);

    skip_gather<<<(N2 + 7) / 8, 256, 0, stream>>>(g3, c2, h2, sk2w, sk2b, g2in, N2);
    run_conv<32, 32>(stream, g2in, ei2, u2, E2, w6, r6, b6, N2, g2, agg, deg);

    skip_gather<<<(N1 + 7) / 8, 256, 0, stream>>>(g2, c1, h1, sk1w, sk1b, g1in, N1);
    run_conv<32, 32>(stream, g1in, ei1, u1, E1, w7, r7, b7, N1, g1, agg, deg);

    // ---- Head ----
    final_logsoftmax<<<(N1 + 255) / 256, 256, 0, stream>>>(g1, fc2w, fc2b, out, N1);
}

// Round 2
// 717.264 us; speedup vs baseline: 1.7896x; 1.7896x over previous
//
#include <hip/hip_runtime.h>
#include <math.h>

// ---------------------------------------------------------------------------
// SplineCNN (ShapeNet part-seg) forward. fp32 throughout.
// Edge convs use k0-bucketed edge lists (count-sorted on device, one sort per
// level shared by all convs of that level) + 8-edges-per-wave batching so the
// 8 corner weight matrices are loaded once per batch instead of once per edge.
// ---------------------------------------------------------------------------

static const int N1 = 10000, E1 = 60000;
static const int N2 = 2500,  E2 = 15000;
static const int N3 = 625,   E3 = 3750;
static const int N4 = 160,   E4 = 960;
static const int NC = 4;
static const int CHUNK = 64;   // edges per block in bucketed edge kernel

__device__ __forceinline__ float eluf(float x) { return x > 0.f ? x : expm1f(x); }

// ---------------------------------------------------------------------------
// Preprocessing: bucket edges by k0 (4x4x4 = 64 buckets), padded to CHUNK.
// ---------------------------------------------------------------------------
__global__ void prep_k0_hist_deg(const float* __restrict__ u, const int* __restrict__ ei, int E,
                                 int* __restrict__ ek0, int* __restrict__ hist,
                                 float* __restrict__ deg) {
    __shared__ int lh[64];
    const int t = threadIdx.x;
    if (t < 64) lh[t] = 0;
    __syncthreads();
    const int e = blockIdx.x * 256 + t;
    int b = -1;
    if (e < E) {
        b = 0;
        #pragma unroll
        for (int d = 0; d < 3; ++d) {
            float v = u[e * 3 + d] * 4.0f;
            float kf = fminf(fmaxf(floorf(v), 0.f), 3.f);
            b = (b << 2) | (int)kf;
        }
        ek0[e] = b;
        atomicAdd(&lh[b], 1);
        atomicAdd(&deg[ei[E + e]], 1.0f);
    }
    __syncthreads();
    if (t < 64 && lh[t]) atomicAdd(&hist[t], lh[t]);
}

// bchunk0[b] = first chunk index of bucket b (buckets padded to CHUNK multiples)
__global__ void scan64(const int* __restrict__ hist, int* __restrict__ bchunk0) {
    __shared__ int sb[65];
    const int t = threadIdx.x;  // 64 threads
    if (t == 0) {
        int cc = 0;
        for (int b = 0; b < 64; ++b) { sb[b] = cc; cc += (hist[b] + CHUNK - 1) / CHUNK; }
        sb[64] = cc;
    }
    __syncthreads();
    bchunk0[t] = sb[t];
    if (t == 0) bchunk0[64] = sb[64];
}

__global__ void fill_chunks(const int* __restrict__ bchunk0, const int* __restrict__ hist,
                            int* __restrict__ ck0, int* __restrict__ ccnt, int maxchunks) {
    const int c = blockIdx.x * 256 + threadIdx.x;
    if (c >= maxchunks) return;
    if (c >= bchunk0[64]) { ccnt[c] = 0; ck0[c] = 0; return; }
    int lo = 0, hi = 64;
    while (hi - lo > 1) { int m = (lo + hi) >> 1; if (bchunk0[m] <= c) lo = m; else hi = m; }
    const int j = c - bchunk0[lo];
    ck0[c] = lo;
    ccnt[c] = min(CHUNK, hist[lo] - j * CHUNK);
}

__global__ void scatter_perm(const int* __restrict__ ek0, int E, const int* __restrict__ bchunk0,
                             int* __restrict__ cursor, int* __restrict__ perm) {
    __shared__ int lh[64], lbase[64];
    const int t = threadIdx.x;
    if (t < 64) lh[t] = 0;
    __syncthreads();
    const int e = blockIdx.x * 256 + t;
    int b = -1, r = 0;
    if (e < E) { b = ek0[e]; r = atomicAdd(&lh[b], 1); }
    __syncthreads();
    if (t < 64) lbase[t] = lh[t] ? atomicAdd(&cursor[t], lh[t]) : 0;
    __syncthreads();
    if (e < E) perm[bchunk0[b] * CHUNK + lbase[b] + r] = e;
}

// ---------------------------------------------------------------------------
// Bucketed edge kernel. Block = CHUNK edges, all with identical k0.
// COUT=64: BLK=512 (8 waves x 8 edges). COUT=32: BLK=256 (4 waves x 16 edges).
// Per wave-batch of 8 edges: x rows from LDS (float4 broadcast), W loaded once,
// acc2[corner][edge] in registers, corner weights folded at writeback.
// ---------------------------------------------------------------------------
template<int CIN, int COUT, int BLK>
__global__ __launch_bounds__(BLK) void bucket_edge(
        const float* __restrict__ x, const int* __restrict__ ei, const float* __restrict__ u,
        const float* __restrict__ W, const int* __restrict__ perm,
        const int* __restrict__ ck0, const int* __restrict__ ccnt,
        float* __restrict__ agg, int E) {
    constexpr int CINP = (CIN + 3) & ~3;
    constexpr int NI4  = CIN / 4;
    __shared__ float xs[CHUNK * CINP];
    __shared__ float wgt[CHUNK * 8];
    __shared__ int pel[CHUNK], srcl[CHUNK], dstl[CHUNK];

    const int chunk = blockIdx.x;
    const int cnt = ccnt[chunk];
    if (cnt == 0) return;
    const int b = ck0[chunk];
    const int kbase = ((b >> 4) & 3) * 25 + ((b >> 2) & 3) * 5 + (b & 3);
    const int cstart = chunk * CHUNK;
    const int tid = threadIdx.x;

    for (int e = tid; e < CHUNK; e += BLK) {
        if (e < cnt) {
            const int pe = perm[cstart + e];
            pel[e] = pe; srcl[e] = ei[pe]; dstl[e] = ei[E + pe];
        } else { pel[e] = -1; srcl[e] = -1; dstl[e] = -1; }
    }
    __syncthreads();
    // corner weights
    for (int t2 = tid; t2 < CHUNK * 8; t2 += BLK) {
        const int e = t2 >> 3, c = t2 & 7;
        float w = 0.f;
        const int pe = pel[e];
        if (pe >= 0) {
            w = 1.f;
            #pragma unroll
            for (int d = 0; d < 3; ++d) {
                float v = u[pe * 3 + d] * 4.0f;
                float kf = fminf(fmaxf(floorf(v), 0.f), 3.f);
                float fr = v - kf;
                const int bd = (c >> (2 - d)) & 1;
                w *= bd ? fr : 1.f - fr;
            }
        }
        wgt[t2] = w;
    }
    // stage x rows
    for (int t2 = tid; t2 < CHUNK * CINP; t2 += BLK) {
        const int e = t2 / CINP, i = t2 - e * CINP;
        const int s = srcl[e];
        xs[t2] = (s >= 0 && i < CIN) ? x[(size_t)s * CIN + i] : 0.f;
    }
    __syncthreads();

    const int lane = tid & 63;
    const int wid  = tid >> 6;
    int o, ehbase;
    if (COUT == 64) { o = lane;      ehbase = wid * 8; }
    else            { o = lane & 31; ehbase = wid * 16 + (lane >> 5) * 8; }

    float acc2[8][8];
    #pragma unroll
    for (int c = 0; c < 8; ++c)
        #pragma unroll
        for (int e = 0; e < 8; ++e) acc2[c][e] = 0.f;

    const float* wb[8];
    #pragma unroll
    for (int c = 0; c < 8; ++c) {
        const int off = ((c >> 2) & 1) * 25 + ((c >> 1) & 1) * 5 + (c & 1);
        wb[c] = W + (size_t)(kbase + off) * (CIN * COUT) + o;
    }

    for (int i4 = 0; i4 < NI4; ++i4) {
        float4 xr[8];
        #pragma unroll
        for (int e = 0; e < 8; ++e)
            xr[e] = *reinterpret_cast<const float4*>(&xs[(ehbase + e) * CINP + i4 * 4]);
        #pragma unroll
        for (int c = 0; c < 8; ++c) {
            const float* wp = wb[c] + (size_t)(i4 * 4) * COUT;
            const float w0 = wp[0], w1 = wp[COUT], w2 = wp[2 * COUT], w3 = wp[3 * COUT];
            #pragma unroll
            for (int e = 0; e < 8; ++e)
                acc2[c][e] += xr[e].x * w0 + xr[e].y * w1 + xr[e].z * w2 + xr[e].w * w3;
        }
    }
    if (CIN % 4) {
        for (int i = NI4 * 4; i < CIN; ++i) {
            float xr1[8];
            #pragma unroll
            for (int e = 0; e < 8; ++e) xr1[e] = xs[(ehbase + e) * CINP + i];
            #pragma unroll
            for (int c = 0; c < 8; ++c) {
                const float w0 = wb[c][(size_t)i * COUT];
                #pragma unroll
                for (int e = 0; e < 8; ++e) acc2[c][e] += xr1[e] * w0;
            }
        }
    }
    #pragma unroll
    for (int e = 0; e < 8; ++e) {
        const int ge = ehbase + e;
        if (ge < cnt) {
            float a = 0.f;
            #pragma unroll
            for (int c = 0; c < 8; ++c) a += wgt[ge * 8 + c] * acc2[c][e];
            atomicAdd(&agg[(size_t)dstl[ge] * COUT + o], a);
        }
    }
}

// out[n,o] = elu( agg[n,o]/max(deg,1) + x[n,:] . R[:,o] + b[o] )
template<int CIN, int COUT>
__global__ void spline_node(const float* __restrict__ x, const float* __restrict__ agg,
                            const float* __restrict__ deg, const float* __restrict__ R,
                            const float* __restrict__ b, float* __restrict__ out, int N) {
    constexpr int NPB = 256 / COUT;
    const int lane = threadIdx.x % COUT;
    const int grp  = threadIdx.x / COUT;
    const int n = blockIdx.x * NPB + grp;
    if (n >= N) return;
    const float d = fmaxf(deg[n], 1.f);
    float s = agg[(size_t)n * COUT + lane] / d + b[lane];
    const float* xs = x + (size_t)n * CIN;
    #pragma unroll 4
    for (int i = 0; i < CIN; ++i) s += xs[i] * R[i * COUT + lane];
    out[(size_t)n * COUT + lane] = eluf(s);
}

// pool buffer [M, C+1]: cols 0..C-1 = -inf (atomic-max identity), col C = 1.0
__global__ void fill_pool(float* __restrict__ p, int M, int C) {
    const int t = blockIdx.x * 256 + threadIdx.x;
    if (t >= M * (C + 1)) return;
    p[t] = (t % (C + 1) == C) ? 1.0f : -INFINITY;
}

__global__ void segmax(const float* __restrict__ h, const int* __restrict__ cl,
                       float* __restrict__ pool, int N, int C, int STRIDE) {
    const int t = blockIdx.x * 256 + threadIdx.x;
    if (t >= N * C) return;
    const int n = t / C, c = t - n * C;
    const float v = h[t];
    float* addr = pool + (size_t)cl[n] * STRIDE + c;
    if (v >= 0.f) atomicMax((int*)addr, __float_as_int(v));
    else          atomicMin((unsigned int*)addr, __float_as_uint(v));
}

__global__ void skip_gather(const float* __restrict__ up, const int* __restrict__ cl,
                            const float* __restrict__ h, const float* __restrict__ skw,
                            const float* __restrict__ skb, float* __restrict__ out, int N) {
    const int lane = threadIdx.x & 31;
    const int grp  = threadIdx.x >> 5;
    const int n = blockIdx.x * 8 + grp;
    if (n >= N) return;
    float s = up[(size_t)cl[n] * 32 + lane] + skb[lane];
    const float* hs = h + (size_t)n * 64;
    #pragma unroll 4
    for (int i = 0; i < 64; ++i) s += hs[i] * skw[i * 32 + lane];
    out[(size_t)n * 32 + lane] = s;
}

__global__ void linear_elu_64_32(const float* __restrict__ x, const float* __restrict__ w,
                                 const float* __restrict__ b, float* __restrict__ out, int N) {
    const int lane = threadIdx.x & 31;
    const int grp  = threadIdx.x >> 5;
    const int n = blockIdx.x * 8 + grp;
    if (n >= N) return;
    float s = b[lane];
    const float* xs = x + (size_t)n * 64;
    #pragma unroll 4
    for (int i = 0; i < 64; ++i) s += xs[i] * w[i * 32 + lane];
    out[(size_t)n * 32 + lane] = eluf(s);
}

__global__ void final_logsoftmax(const float* __restrict__ g1, const float* __restrict__ w,
                                 const float* __restrict__ b, float* __restrict__ out, int N) {
    const int n = blockIdx.x * 256 + threadIdx.x;
    if (n >= N) return;
    const float* xs = g1 + (size_t)n * 32;
    float v[NC];
    #pragma unroll
    for (int o = 0; o < NC; ++o) {
        float s = b[o];
        #pragma unroll
        for (int i = 0; i < 32; ++i) s += xs[i] * w[i * NC + o];
        v[o] = s;
    }
    const float m = fmaxf(fmaxf(v[0], v[1]), fmaxf(v[2], v[3]));
    float se = 0.f;
    #pragma unroll
    for (int o = 0; o < NC; ++o) se += expf(v[o] - m);
    const float l = logf(se);
    #pragma unroll
    for (int o = 0; o < NC; ++o) out[(size_t)n * NC + o] = v[o] - m - l;
}

// ---------------------------------------------------------------------------
// Host orchestration
// ---------------------------------------------------------------------------
struct Level {
    const int* ei; const float* u; int E; int maxchunks;
    int *ek0, *hist, *bchunk0, *cursor, *ck0, *ccnt, *perm;
    float* deg;
};

template<int CIN, int COUT>
static void run_bconv(hipStream_t s, const float* x, const float* W, const float* R,
                      const float* bb, int N, float* out, float* agg, const Level& L) {
    (void)hipMemsetAsync(agg, 0, (size_t)N * COUT * sizeof(float), s);
    constexpr int BLK = (COUT == 64) ? 512 : 256;
    bucket_edge<CIN, COUT, BLK><<<L.maxchunks, BLK, 0, s>>>(
        x, L.ei, L.u, W, L.perm, L.ck0, L.ccnt, agg, L.E);
    constexpr int NPB = 256 / COUT;
    spline_node<CIN, COUT><<<(N + NPB - 1) / NPB, 256, 0, s>>>(x, agg, L.deg, R, bb, out, N);
}

extern "C" void kernel_launch(void* const* d_in, const int* in_sizes, int n_in,
                              void* d_out, int out_size, void* d_ws, size_t ws_size,
                              hipStream_t stream) {
    const float* x    = (const float*)d_in[0];
    const int*   ei1  = (const int*)  d_in[1];
    const float* u1   = (const float*)d_in[2];
    const int*   ei2  = (const int*)  d_in[3];
    const float* u2   = (const float*)d_in[4];
    const int*   ei3  = (const int*)  d_in[5];
    const float* u3   = (const float*)d_in[6];
    const int*   ei4  = (const int*)  d_in[7];
    const float* u4   = (const float*)d_in[8];
    const int*   c1   = (const int*)  d_in[9];
    const int*   c2   = (const int*)  d_in[10];
    const int*   c3   = (const int*)  d_in[11];
    const float *w1  = (const float*)d_in[12], *r1  = (const float*)d_in[13], *b1  = (const float*)d_in[14];
    const float *w12 = (const float*)d_in[15], *r12 = (const float*)d_in[16], *b12 = (const float*)d_in[17];
    const float *w2  = (const float*)d_in[18], *r2  = (const float*)d_in[19], *b2  = (const float*)d_in[20];
    const float *w22 = (const float*)d_in[21], *r22 = (const float*)d_in[22], *b22 = (const float*)d_in[23];
    const float *w3  = (const float*)d_in[24], *r3  = (const float*)d_in[25], *b3  = (const float*)d_in[26];
    const float *w32 = (const float*)d_in[27], *r32 = (const float*)d_in[28], *b32 = (const float*)d_in[29];
    const float *w4  = (const float*)d_in[30], *r4  = (const float*)d_in[31], *b4  = (const float*)d_in[32];
    const float *w42 = (const float*)d_in[33], *r42 = (const float*)d_in[34], *b42 = (const float*)d_in[35];
    const float *w5  = (const float*)d_in[36], *r5  = (const float*)d_in[37], *b5  = (const float*)d_in[38];
    const float *w6  = (const float*)d_in[39], *r6  = (const float*)d_in[40], *b6  = (const float*)d_in[41];
    const float *w7  = (const float*)d_in[42], *r7  = (const float*)d_in[43], *b7  = (const float*)d_in[44];
    const float *fc1w = (const float*)d_in[45], *fc1b = (const float*)d_in[46];
    const float *fc2w = (const float*)d_in[47], *fc2b = (const float*)d_in[48];
    const float *sk1w = (const float*)d_in[49], *sk1b = (const float*)d_in[50];
    const float *sk2w = (const float*)d_in[51], *sk2b = (const float*)d_in[52];
    const float *sk3w = (const float*)d_in[53], *sk3b = (const float*)d_in[54];
    float* out = (float*)d_out;

    // byte bump allocator, 256B aligned
    char* wsb = (char*)d_ws;
    size_t off = 0;
    auto alloc = [&](size_t bytes) {
        void* p = wsb + off; off = (off + bytes + 255) & ~(size_t)255; return p;
    };
    auto allocF = [&](size_t n) { return (float*)alloc(n * 4); };
    auto allocI = [&](size_t n) { return (int*)alloc(n * 4); };

    float* h1a  = allocF((size_t)N1 * 64);
    float* h1   = allocF((size_t)N1 * 64);
    float* h2in = allocF((size_t)N2 * 65);
    float* h2a  = allocF((size_t)N2 * 64);
    float* h2   = allocF((size_t)N2 * 64);
    float* h3in = allocF((size_t)N3 * 65);
    float* h3a  = allocF((size_t)N3 * 64);
    float* h3   = allocF((size_t)N3 * 64);
    float* h4in = allocF((size_t)N4 * 65);
    float* h4a  = allocF((size_t)N4 * 64);
    float* h4b  = allocF((size_t)N4 * 64);
    float* h4c  = allocF((size_t)N4 * 64);
    float* h4   = allocF((size_t)N4 * 32);
    float* g3in = allocF((size_t)N3 * 32);
    float* g3   = allocF((size_t)N3 * 32);
    float* g2in = allocF((size_t)N2 * 32);
    float* g2   = allocF((size_t)N2 * 32);
    float* g1in = allocF((size_t)N1 * 32);
    float* g1   = allocF((size_t)N1 * 32);
    float* agg  = allocF((size_t)N1 * 64);

    Level L[4];
    const int*   eis[4] = {ei1, ei2, ei3, ei4};
    const float* us [4] = {u1, u2, u3, u4};
    const int    Es [4] = {E1, E2, E3, E4};
    const int    Ns [4] = {N1, N2, N3, N4};
    for (int l = 0; l < 4; ++l) {
        L[l].ei = eis[l]; L[l].u = us[l]; L[l].E = Es[l];
        L[l].maxchunks = (Es[l] + CHUNK - 1) / CHUNK + 64;
        L[l].ek0     = allocI(Es[l]);
        L[l].hist    = allocI(64);
        L[l].bchunk0 = allocI(65);
        L[l].cursor  = allocI(64);
        L[l].ck0     = allocI(L[l].maxchunks);
        L[l].ccnt    = allocI(L[l].maxchunks);
        L[l].perm    = allocI((size_t)L[l].maxchunks * CHUNK);
        L[l].deg     = allocF(Ns[l]);
    }

    // ---- preprocessing: one bucket-sort + degree per level ----
    for (int l = 0; l < 4; ++l) {
        (void)hipMemsetAsync(L[l].hist,   0, 64 * 4, stream);
        (void)hipMemsetAsync(L[l].cursor, 0, 64 * 4, stream);
        (void)hipMemsetAsync(L[l].deg,    0, Ns[l] * 4, stream);
        const int E = L[l].E;
        prep_k0_hist_deg<<<(E + 255) / 256, 256, 0, stream>>>(
            L[l].u, L[l].ei, E, L[l].ek0, L[l].hist, L[l].deg);
        scan64<<<1, 64, 0, stream>>>(L[l].hist, L[l].bchunk0);
        fill_chunks<<<(L[l].maxchunks + 255) / 256, 256, 0, stream>>>(
            L[l].bchunk0, L[l].hist, L[l].ck0, L[l].ccnt, L[l].maxchunks);
        scatter_perm<<<(E + 255) / 256, 256, 0, stream>>>(
            L[l].ek0, E, L[l].bchunk0, L[l].cursor, L[l].perm);
    }

    // ---- Level 1 ----
    run_bconv<1, 64>(stream, x,   w1,  r1,  b1,  N1, h1a, agg, L[0]);
    run_bconv<64, 64>(stream, h1a, w12, r12, b12, N1, h1,  agg, L[0]);

    fill_pool<<<(N2 * 65 + 255) / 256, 256, 0, stream>>>(h2in, N2, 64);
    segmax<<<(N1 * 64 + 255) / 256, 256, 0, stream>>>(h1, c1, h2in, N1, 64, 65);

    // ---- Level 2 ----
    run_bconv<65, 64>(stream, h2in, w2,  r2,  b2,  N2, h2a, agg, L[1]);
    run_bconv<64, 64>(stream, h2a,  w22, r22, b22, N2, h2,  agg, L[1]);

    fill_pool<<<(N3 * 65 + 255) / 256, 256, 0, stream>>>(h3in, N3, 64);
    segmax<<<(N2 * 64 + 255) / 256, 256, 0, stream>>>(h2, c2, h3in, N2, 64, 65);

    // ---- Level 3 ----
    run_bconv<65, 64>(stream, h3in, w3,  r3,  b3,  N3, h3a, agg, L[2]);
    run_bconv<64, 64>(stream, h3a,  w32, r32, b32, N3, h3,  agg, L[2]);

    fill_pool<<<(N4 * 65 + 255) / 256, 256, 0, stream>>>(h4in, N4, 64);
    segmax<<<(N3 * 64 + 255) / 256, 256, 0, stream>>>(h3, c3, h4in, N3, 64, 65);

    // ---- Level 4 ----
    run_bconv<65, 64>(stream, h4in, w4,  r4,  b4,  N4, h4a, agg, L[3]);
    run_bconv<64, 64>(stream, h4a,  w42, r42, b42, N4, h4b, agg, L[3]);
    run_bconv<64, 64>(stream, h4b,  w42, r42, b42, N4, h4c, agg, L[3]); // applied twice

    linear_elu_64_32<<<(N4 + 7) / 8, 256, 0, stream>>>(h4c, fc1w, fc1b, h4, N4);

    // ---- Decoder ----
    skip_gather<<<(N3 + 7) / 8, 256, 0, stream>>>(h4, c3, h3, sk3w, sk3b, g3in, N3);
    run_bconv<32, 32>(stream, g3in, w5, r5, b5, N3, g3, agg, L[2]);

    skip_gather<<<(N2 + 7) / 8, 256, 0, stream>>>(g3, c2, h2, sk2w, sk2b, g2in, N2);
    run_bconv<32, 32>(stream, g2in, w6, r6, b6, N2, g2, agg, L[1]);

    skip_gather<<<(N1 + 7) / 8, 256, 0, stream>>>(g2, c1, h1, sk1w, sk1b, g1in, N1);
    run_bconv<32, 32>(stream, g1in, w7, r7, b7, N1, g1, agg, L[0]);

    // ---- Head ----
    final_logsoftmax<<<(N1 + 255) / 256, 256, 0, stream>>>(g1, fc2w, fc2b, out, N1);
}

// Round 3
// 366.200 us; speedup vs baseline: 3.5053x; 1.9587x over previous
//
#include <hip/hip_runtime.h>
#include <math.h>

// ---------------------------------------------------------------------------
// SplineCNN forward. Edge message GEMMs in bf16 MFMA (fp32 accumulate),
// everything else fp32. k0-bucketed edges (device count-sort, one per level).
// ---------------------------------------------------------------------------

static const int N1 = 10000, E1 = 60000;
static const int N2 = 2500,  E2 = 15000;
static const int N3 = 625,   E3 = 3750;
static const int N4 = 160,   E4 = 960;
static const int NC = 4;
static const int CHUNK = 64;

typedef __attribute__((ext_vector_type(8))) short bfrag;
typedef __attribute__((ext_vector_type(4))) float f32x4;

__device__ __forceinline__ float eluf(float x) { return x > 0.f ? x : expm1f(x); }

__device__ __forceinline__ unsigned short bfc(float f) {   // f32 -> bf16 RNE
    unsigned u = __float_as_uint(f);
    return (unsigned short)((u + 0x7FFF + ((u >> 16) & 1)) >> 16);
}

// ---------------------------------------------------------------------------
// Preprocessing: bucket edges by k0 (4^3 = 64 buckets), padded to CHUNK.
// ---------------------------------------------------------------------------
__global__ void prep_k0_hist_deg(const float* __restrict__ u, const int* __restrict__ ei, int E,
                                 int* __restrict__ ek0, int* __restrict__ hist,
                                 float* __restrict__ deg) {
    __shared__ int lh[64];
    const int t = threadIdx.x;
    if (t < 64) lh[t] = 0;
    __syncthreads();
    const int e = blockIdx.x * 256 + t;
    if (e < E) {
        int b = 0;
        #pragma unroll
        for (int d = 0; d < 3; ++d) {
            float v = u[e * 3 + d] * 4.0f;
            float kf = fminf(fmaxf(floorf(v), 0.f), 3.f);
            b = (b << 2) | (int)kf;
        }
        ek0[e] = b;
        atomicAdd(&lh[b], 1);
        atomicAdd(&deg[ei[E + e]], 1.0f);
    }
    __syncthreads();
    if (t < 64 && lh[t]) atomicAdd(&hist[t], lh[t]);
}

__global__ void scan64(const int* __restrict__ hist, int* __restrict__ bchunk0) {
    __shared__ int sb[65];
    const int t = threadIdx.x;  // 64 threads
    if (t == 0) {
        int cc = 0;
        for (int b = 0; b < 64; ++b) { sb[b] = cc; cc += (hist[b] + CHUNK - 1) / CHUNK; }
        sb[64] = cc;
    }
    __syncthreads();
    bchunk0[t] = sb[t];
    if (t == 0) bchunk0[64] = sb[64];
}

__global__ void fill_chunks(const int* __restrict__ bchunk0, const int* __restrict__ hist,
                            int* __restrict__ ck0, int* __restrict__ ccnt, int maxchunks) {
    const int c = blockIdx.x * 256 + threadIdx.x;
    if (c >= maxchunks) return;
    if (c >= bchunk0[64]) { ccnt[c] = 0; ck0[c] = 0; return; }
    int lo = 0, hi = 64;
    while (hi - lo > 1) { int m = (lo + hi) >> 1; if (bchunk0[m] <= c) lo = m; else hi = m; }
    const int j = c - bchunk0[lo];
    ck0[c] = lo;
    ccnt[c] = min(CHUNK, hist[lo] - j * CHUNK);
}

__global__ void scatter_perm(const int* __restrict__ ek0, int E, const int* __restrict__ bchunk0,
                             int* __restrict__ cursor, int* __restrict__ perm) {
    __shared__ int lh[64], lbase[64];
    const int t = threadIdx.x;
    if (t < 64) lh[t] = 0;
    __syncthreads();
    const int e = blockIdx.x * 256 + t;
    int b = -1, r = 0;
    if (e < E) { b = ek0[e]; r = atomicAdd(&lh[b], 1); }
    __syncthreads();
    if (t < 64) lbase[t] = lh[t] ? atomicAdd(&cursor[t], lh[t]) : 0;
    __syncthreads();
    if (e < E) perm[bchunk0[b] * CHUNK + lbase[b] + r] = e;
}

// ---------------------------------------------------------------------------
// W -> bf16 MFMA-packed layout:  Wt[((k*KG + i/8)*COUT + o)*8 + i%8]
// ---------------------------------------------------------------------------
struct WtDesc { const float* src; unsigned short* dst; int cinmat, xs, cout; };
struct WtDescs { WtDesc d[10]; };

__global__ void convert_wt(WtDescs ds) {
    const WtDesc w = ds.d[blockIdx.y];
    const int total = 125 * w.cinmat * w.cout;
    const int t = blockIdx.x * 256 + threadIdx.x;
    if (t >= total) return;
    const int o = t % w.cout;
    const int rest = t / w.cout;
    const int i = rest % w.cinmat;
    const int k = rest / w.cinmat;
    const float v = w.src[((size_t)k * w.xs + i) * w.cout + o];
    const int KG = w.cinmat >> 3;
    w.dst[(((size_t)(k * KG + (i >> 3))) * w.cout + o) * 8 + (i & 7)] = bfc(v);
}

// ---------------------------------------------------------------------------
// MFMA bucket-GEMM edge kernel. Block = 64 edges (one chunk), 256 threads =
// 4 waves; wave w owns edges [16w,16w+16) x all COUT outs.
// A0 = (1-f2)*x, A1 = f2*x  (bf16, LDS); 4 accumulators (one per (b0,b1));
// g_q folded in epilogue; CIN=65 ones-column folded as epilogue bias.
// ---------------------------------------------------------------------------
template<int CINMAT, int COUT, bool HAS_ONES>
__global__ __launch_bounds__(256) void bucket_gemm(
        const float* __restrict__ x, const int* __restrict__ ei, const float* __restrict__ u,
        const unsigned short* __restrict__ Wt, const float* __restrict__ Wf,
        const int* __restrict__ perm, const int* __restrict__ ck0, const int* __restrict__ ccnt,
        float* __restrict__ agg, int E) {
    constexpr int ALDA = CINMAT + 8;       // bf16 elems per LDS row (conflict spread)
    constexpr int KG   = CINMAT / 8;       // k-groups per kernel matrix
    constexpr int NT   = COUT / 16;        // N tiles per wave
    constexpr int HALVES = CINMAT / 32;    // K slabs per corner
    constexpr int XS   = CINMAT + (HAS_ONES ? 1 : 0);
    constexpr int IT   = CINMAT / 4;       // x elems staged per thread

    __shared__ unsigned short A0s[64 * ALDA], A1s[64 * ALDA];
    __shared__ float gS[64 * 4], sS[64 * 2];
    __shared__ int srcS[64], dstS[64];
    __shared__ float WonesS[HAS_ONES ? 8 * COUT : 4];

    const int chunk = blockIdx.x;
    const int cnt = ccnt[chunk];
    if (cnt == 0) return;
    const int b = ck0[chunk];
    const int kbase = ((b >> 4) & 3) * 25 + ((b >> 2) & 3) * 5 + (b & 3);
    const int cstart = chunk * CHUNK;
    const int tid = threadIdx.x;

    // ---- phase A: per-edge meta ----
    if (tid < CHUNK) {
        const int e = tid;
        const int pe = (e < cnt) ? perm[cstart + e] : -1;
        int sv = -1, dv = 0;
        float g0 = 0, g1 = 0, g2 = 0, g3 = 0, s0 = 0, s1 = 0;
        if (pe >= 0) {
            sv = ei[pe]; dv = ei[E + pe];
            float f[3];
            #pragma unroll
            for (int d2 = 0; d2 < 3; ++d2) {
                const float v = u[pe * 3 + d2] * 4.f;
                const float kf = fminf(fmaxf(floorf(v), 0.f), 3.f);
                f[d2] = v - kf;
            }
            g0 = (1.f - f[0]) * (1.f - f[1]); g1 = (1.f - f[0]) * f[1];
            g2 = f[0] * (1.f - f[1]);         g3 = f[0] * f[1];
            s0 = 1.f - f[2]; s1 = f[2];
        }
        srcS[e] = sv; dstS[e] = dv;
        gS[e * 4 + 0] = g0; gS[e * 4 + 1] = g1; gS[e * 4 + 2] = g2; gS[e * 4 + 3] = g3;
        sS[e * 2 + 0] = s0; sS[e * 2 + 1] = s1;
    }
    if (HAS_ONES) {
        for (int t2 = tid; t2 < 8 * COUT; t2 += 256) {
            const int c = t2 / COUT, o = t2 % COUT;
            const int koff = ((c >> 2) & 1) * 25 + ((c >> 1) & 1) * 5 + (c & 1);
            WonesS[t2] = Wf[((size_t)(kbase + koff) * XS + CINMAT) * COUT + o];
        }
    }
    __syncthreads();

    // ---- phase B: stage A0/A1 (bf16) ----
    {
        const int e  = tid >> 2;
        const int ib = (tid & 3) * IT;
        const int sv = srcS[e];
        const float sc0 = sS[e * 2], sc1 = sS[e * 2 + 1];
        #pragma unroll
        for (int j = 0; j < IT; j += 2) {
            float x0 = 0.f, x1 = 0.f;
            if (sv >= 0) {
                x0 = x[(size_t)sv * XS + ib + j];
                x1 = x[(size_t)sv * XS + ib + j + 1];
            }
            const unsigned p0 = bfc(x0 * sc0) | ((unsigned)bfc(x1 * sc0) << 16);
            const unsigned p1 = bfc(x0 * sc1) | ((unsigned)bfc(x1 * sc1) << 16);
            *(unsigned*)&A0s[e * ALDA + ib + j] = p0;
            *(unsigned*)&A1s[e * ALDA + ib + j] = p1;
        }
    }
    __syncthreads();

    // ---- main loop ----
    const int lane = tid & 63;
    const int wid  = tid >> 6;
    const int m0   = wid * 16;
    const int arow = m0 + (lane & 15);
    const int kg   = lane >> 4;
    const int ocol = lane & 15;

    f32x4 acc[4][NT];
    #pragma unroll
    for (int q = 0; q < 4; ++q)
        #pragma unroll
        for (int nt = 0; nt < NT; ++nt) acc[q][nt] = (f32x4){0.f, 0.f, 0.f, 0.f};

    #pragma unroll
    for (int q = 0; q < 4; ++q) {
        #pragma unroll
        for (int b2 = 0; b2 < 2; ++b2) {
            const unsigned short* Ab = b2 ? A1s : A0s;
            const int koff = (q >> 1) * 25 + (q & 1) * 5 + b2;
            #pragma unroll
            for (int hf = 0; hf < HALVES; ++hf) {
                const bfrag a = *(const bfrag*)(Ab + arow * ALDA + hf * 32 + kg * 8);
                const int krow = (kbase + koff) * KG + hf * 4 + kg;
                #pragma unroll
                for (int nt = 0; nt < NT; ++nt) {
                    const bfrag bb = *(const bfrag*)(Wt + ((size_t)krow * COUT + nt * 16 + ocol) * 8);
                    acc[q][nt] = __builtin_amdgcn_mfma_f32_16x16x32_bf16(a, bb, acc[q][nt], 0, 0, 0);
                }
            }
        }
    }

    // ---- epilogue: fold g_q (+ ones bias), atomic scatter ----
    const int grp = lane >> 4;
    #pragma unroll
    for (int nt = 0; nt < NT; ++nt) {
        const int o = nt * 16 + ocol;
        float wo[8];
        if (HAS_ONES) {
            #pragma unroll
            for (int c = 0; c < 8; ++c) wo[c] = WonesS[c * COUT + o];
        }
        #pragma unroll
        for (int r = 0; r < 4; ++r) {
            const int e = m0 + grp * 4 + r;
            if (e < cnt) {
                const float g0 = gS[e * 4 + 0], g1 = gS[e * 4 + 1];
                const float g2 = gS[e * 4 + 2], g3 = gS[e * 4 + 3];
                float v = g0 * acc[0][nt][r] + g1 * acc[1][nt][r] +
                          g2 * acc[2][nt][r] + g3 * acc[3][nt][r];
                if (HAS_ONES) {
                    const float s0v = sS[e * 2], s1v = sS[e * 2 + 1];
                    v += g0 * (s0v * wo[0] + s1v * wo[1]) + g1 * (s0v * wo[2] + s1v * wo[3]) +
                         g2 * (s0v * wo[4] + s1v * wo[5]) + g3 * (s0v * wo[6] + s1v * wo[7]);
                }
                atomicAdd(&agg[(size_t)dstS[e] * COUT + o], v);
            }
        }
    }
}

// ---------------------------------------------------------------------------
// conv1 (CIN=1) fp32 edge kernel (old path, cheap)
// ---------------------------------------------------------------------------
template<int CIN, int COUT, int BLK>
__global__ __launch_bounds__(BLK) void bucket_edge(
        const float* __restrict__ x, const int* __restrict__ ei, const float* __restrict__ u,
        const float* __restrict__ W, const int* __restrict__ perm,
        const int* __restrict__ ck0, const int* __restrict__ ccnt,
        float* __restrict__ agg, int E) {
    constexpr int CINP = (CIN + 3) & ~3;
    __shared__ float xs[CHUNK * CINP];
    __shared__ float wgt[CHUNK * 8];
    __shared__ int pel[CHUNK], srcl[CHUNK], dstl[CHUNK];

    const int chunk = blockIdx.x;
    const int cnt = ccnt[chunk];
    if (cnt == 0) return;
    const int b = ck0[chunk];
    const int kbase = ((b >> 4) & 3) * 25 + ((b >> 2) & 3) * 5 + (b & 3);
    const int cstart = chunk * CHUNK;
    const int tid = threadIdx.x;

    for (int e = tid; e < CHUNK; e += BLK) {
        if (e < cnt) {
            const int pe = perm[cstart + e];
            pel[e] = pe; srcl[e] = ei[pe]; dstl[e] = ei[E + pe];
        } else { pel[e] = -1; srcl[e] = -1; dstl[e] = -1; }
    }
    __syncthreads();
    for (int t2 = tid; t2 < CHUNK * 8; t2 += BLK) {
        const int e = t2 >> 3, c = t2 & 7;
        float w = 0.f;
        const int pe = pel[e];
        if (pe >= 0) {
            w = 1.f;
            #pragma unroll
            for (int d = 0; d < 3; ++d) {
                const float v = u[pe * 3 + d] * 4.0f;
                const float kf = fminf(fmaxf(floorf(v), 0.f), 3.f);
                const float fr = v - kf;
                const int bd = (c >> (2 - d)) & 1;
                w *= bd ? fr : 1.f - fr;
            }
        }
        wgt[t2] = w;
    }
    for (int t2 = tid; t2 < CHUNK * CINP; t2 += BLK) {
        const int e = t2 / CINP, i = t2 - e * CINP;
        const int s = srcl[e];
        xs[t2] = (s >= 0 && i < CIN) ? x[(size_t)s * CIN + i] : 0.f;
    }
    __syncthreads();

    const int lane = tid & 63;
    const int wid  = tid >> 6;
    const int o = lane;
    const int ehbase = wid * 8;

    float acc2[8][8];
    #pragma unroll
    for (int c = 0; c < 8; ++c)
        #pragma unroll
        for (int e = 0; e < 8; ++e) acc2[c][e] = 0.f;

    for (int i = 0; i < CIN; ++i) {
        float xr1[8];
        #pragma unroll
        for (int e = 0; e < 8; ++e) xr1[e] = xs[(ehbase + e) * CINP + i];
        #pragma unroll
        for (int c = 0; c < 8; ++c) {
            const int off = ((c >> 2) & 1) * 25 + ((c >> 1) & 1) * 5 + (c & 1);
            const float w0 = W[(size_t)(kbase + off) * (CIN * COUT) + (size_t)i * COUT + o];
            #pragma unroll
            for (int e = 0; e < 8; ++e) acc2[c][e] += xr1[e] * w0;
        }
    }
    #pragma unroll
    for (int e = 0; e < 8; ++e) {
        const int ge = ehbase + e;
        if (ge < cnt) {
            float a = 0.f;
            #pragma unroll
            for (int c = 0; c < 8; ++c) a += wgt[ge * 8 + c] * acc2[c][e];
            atomicAdd(&agg[(size_t)dstl[ge] * COUT + o], a);
        }
    }
}

// out[n,o] = elu( agg[n,o]/max(deg,1) + x[n,:] . R[:,o] + b[o] )
template<int CIN, int COUT>
__global__ void spline_node(const float* __restrict__ x, const float* __restrict__ agg,
                            const float* __restrict__ deg, const float* __restrict__ R,
                            const float* __restrict__ b, float* __restrict__ out, int N) {
    constexpr int NPB = 256 / COUT;
    const int lane = threadIdx.x % COUT;
    const int grp  = threadIdx.x / COUT;
    const int n = blockIdx.x * NPB + grp;
    if (n >= N) return;
    const float d = fmaxf(deg[n], 1.f);
    float s = agg[(size_t)n * COUT + lane] / d + b[lane];
    const float* xs = x + (size_t)n * CIN;
    #pragma unroll 4
    for (int i = 0; i < CIN; ++i) s += xs[i] * R[i * COUT + lane];
    out[(size_t)n * COUT + lane] = eluf(s);
}

__global__ void fill_pool(float* __restrict__ p, int M, int C) {
    const int t = blockIdx.x * 256 + threadIdx.x;
    if (t >= M * (C + 1)) return;
    p[t] = (t % (C + 1) == C) ? 1.0f : -INFINITY;
}

__global__ void segmax(const float* __restrict__ h, const int* __restrict__ cl,
                       float* __restrict__ pool, int N, int C, int STRIDE) {
    const int t = blockIdx.x * 256 + threadIdx.x;
    if (t >= N * C) return;
    const int n = t / C, c = t - n * C;
    const float v = h[t];
    float* addr = pool + (size_t)cl[n] * STRIDE + c;
    if (v >= 0.f) atomicMax((int*)addr, __float_as_int(v));
    else          atomicMin((unsigned int*)addr, __float_as_uint(v));
}

__global__ void skip_gather(const float* __restrict__ up, const int* __restrict__ cl,
                            const float* __restrict__ h, const float* __restrict__ skw,
                            const float* __restrict__ skb, float* __restrict__ out, int N) {
    const int lane = threadIdx.x & 31;
    const int grp  = threadIdx.x >> 5;
    const int n = blockIdx.x * 8 + grp;
    if (n >= N) return;
    float s = up[(size_t)cl[n] * 32 + lane] + skb[lane];
    const float* hs = h + (size_t)n * 64;
    #pragma unroll 4
    for (int i = 0; i < 64; ++i) s += hs[i] * skw[i * 32 + lane];
    out[(size_t)n * 32 + lane] = s;
}

__global__ void linear_elu_64_32(const float* __restrict__ x, const float* __restrict__ w,
                                 const float* __restrict__ b, float* __restrict__ out, int N) {
    const int lane = threadIdx.x & 31;
    const int grp  = threadIdx.x >> 5;
    const int n = blockIdx.x * 8 + grp;
    if (n >= N) return;
    float s = b[lane];
    const float* xs = x + (size_t)n * 64;
    #pragma unroll 4
    for (int i = 0; i < 64; ++i) s += xs[i] * w[i * 32 + lane];
    out[(size_t)n * 32 + lane] = eluf(s);
}

__global__ void final_logsoftmax(const float* __restrict__ g1, const float* __restrict__ w,
                                 const float* __restrict__ b, float* __restrict__ out, int N) {
    const int n = blockIdx.x * 256 + threadIdx.x;
    if (n >= N) return;
    const float* xs = g1 + (size_t)n * 32;
    float v[NC];
    #pragma unroll
    for (int o = 0; o < NC; ++o) {
        float s = b[o];
        #pragma unroll
        for (int i = 0; i < 32; ++i) s += xs[i] * w[i * NC + o];
        v[o] = s;
    }
    const float m = fmaxf(fmaxf(v[0], v[1]), fmaxf(v[2], v[3]));
    float se = 0.f;
    #pragma unroll
    for (int o = 0; o < NC; ++o) se += expf(v[o] - m);
    const float l = logf(se);
    #pragma unroll
    for (int o = 0; o < NC; ++o) out[(size_t)n * NC + o] = v[o] - m - l;
}

// ---------------------------------------------------------------------------
// Host orchestration
// ---------------------------------------------------------------------------
struct Level {
    const int* ei; const float* u; int E; int maxchunks;
    int *ek0, *hist, *cursor, *bchunk0, *ck0, *ccnt, *perm;
    float* deg;
};

template<int CINMAT, int COUT, bool HAS_ONES>
static void run_gemm_conv(hipStream_t s, const float* x, const unsigned short* Wt,
                          const float* Wf, const float* R, const float* bb, int N,
                          float* out, float* agg, const Level& L) {
    (void)hipMemsetAsync(agg, 0, (size_t)N * COUT * sizeof(float), s);
    bucket_gemm<CINMAT, COUT, HAS_ONES><<<L.maxchunks, 256, 0, s>>>(
        x, L.ei, L.u, Wt, Wf, L.perm, L.ck0, L.ccnt, agg, L.E);
    constexpr int CIN = CINMAT + (HAS_ONES ? 1 : 0);
    constexpr int NPB = 256 / COUT;
    spline_node<CIN, COUT><<<(N + NPB - 1) / NPB, 256, 0, s>>>(x, agg, L.deg, R, bb, out, N);
}

extern "C" void kernel_launch(void* const* d_in, const int* in_sizes, int n_in,
                              void* d_out, int out_size, void* d_ws, size_t ws_size,
                              hipStream_t stream) {
    const float* x    = (const float*)d_in[0];
    const int*   ei1  = (const int*)  d_in[1];
    const float* u1   = (const float*)d_in[2];
    const int*   ei2  = (const int*)  d_in[3];
    const float* u2   = (const float*)d_in[4];
    const int*   ei3  = (const int*)  d_in[5];
    const float* u3   = (const float*)d_in[6];
    const int*   ei4  = (const int*)  d_in[7];
    const float* u4   = (const float*)d_in[8];
    const int*   c1   = (const int*)  d_in[9];
    const int*   c2   = (const int*)  d_in[10];
    const int*   c3   = (const int*)  d_in[11];
    const float *w1  = (const float*)d_in[12], *r1  = (const float*)d_in[13], *b1  = (const float*)d_in[14];
    const float *w12 = (const float*)d_in[15], *r12 = (const float*)d_in[16], *b12 = (const float*)d_in[17];
    const float *w2  = (const float*)d_in[18], *r2  = (const float*)d_in[19], *b2  = (const float*)d_in[20];
    const float *w22 = (const float*)d_in[21], *r22 = (const float*)d_in[22], *b22 = (const float*)d_in[23];
    const float *w3  = (const float*)d_in[24], *r3  = (const float*)d_in[25], *b3  = (const float*)d_in[26];
    const float *w32 = (const float*)d_in[27], *r32 = (const float*)d_in[28], *b32 = (const float*)d_in[29];
    const float *w4  = (const float*)d_in[30], *r4  = (const float*)d_in[31], *b4  = (const float*)d_in[32];
    const float *w42 = (const float*)d_in[33], *r42 = (const float*)d_in[34], *b42 = (const float*)d_in[35];
    const float *w5  = (const float*)d_in[36], *r5  = (const float*)d_in[37], *b5  = (const float*)d_in[38];
    const float *w6  = (const float*)d_in[39], *r6  = (const float*)d_in[40], *b6  = (const float*)d_in[41];
    const float *w7  = (const float*)d_in[42], *r7  = (const float*)d_in[43], *b7  = (const float*)d_in[44];
    const float *fc1w = (const float*)d_in[45], *fc1b = (const float*)d_in[46];
    const float *fc2w = (const float*)d_in[47], *fc2b = (const float*)d_in[48];
    const float *sk1w = (const float*)d_in[49], *sk1b = (const float*)d_in[50];
    const float *sk2w = (const float*)d_in[51], *sk2b = (const float*)d_in[52];
    const float *sk3w = (const float*)d_in[53], *sk3b = (const float*)d_in[54];
    float* out = (float*)d_out;

    char* wsb = (char*)d_ws;
    size_t off = 0;
    auto alloc = [&](size_t bytes) {
        void* p = wsb + off; off = (off + bytes + 255) & ~(size_t)255; return p;
    };
    auto allocF = [&](size_t n) { return (float*)alloc(n * 4); };
    auto allocI = [&](size_t n) { return (int*)alloc(n * 4); };
    auto allocH = [&](size_t n) { return (unsigned short*)alloc(n * 2); };

    float* h1a  = allocF((size_t)N1 * 64);
    float* h1   = allocF((size_t)N1 * 64);
    float* h2in = allocF((size_t)N2 * 65);
    float* h2a  = allocF((size_t)N2 * 64);
    float* h2   = allocF((size_t)N2 * 64);
    float* h3in = allocF((size_t)N3 * 65);
    float* h3a  = allocF((size_t)N3 * 64);
    float* h3   = allocF((size_t)N3 * 64);
    float* h4in = allocF((size_t)N4 * 65);
    float* h4a  = allocF((size_t)N4 * 64);
    float* h4b  = allocF((size_t)N4 * 64);
    float* h4c  = allocF((size_t)N4 * 64);
    float* h4   = allocF((size_t)N4 * 32);
    float* g3in = allocF((size_t)N3 * 32);
    float* g3   = allocF((size_t)N3 * 32);
    float* g2in = allocF((size_t)N2 * 32);
    float* g2   = allocF((size_t)N2 * 32);
    float* g1in = allocF((size_t)N1 * 32);
    float* g1   = allocF((size_t)N1 * 32);
    float* agg  = allocF((size_t)N1 * 64);

    // bf16 packed weight banks
    const size_t SZ64 = (size_t)125 * 8 * 64 * 8;   // CINMAT=64, COUT=64
    const size_t SZ32 = (size_t)125 * 4 * 32 * 8;   // CINMAT=32, COUT=32
    unsigned short* t12 = allocH(SZ64);
    unsigned short* t22 = allocH(SZ64);
    unsigned short* t32 = allocH(SZ64);
    unsigned short* t42 = allocH(SZ64);
    unsigned short* t2  = allocH(SZ64);
    unsigned short* t3  = allocH(SZ64);
    unsigned short* t4  = allocH(SZ64);
    unsigned short* t5  = allocH(SZ32);
    unsigned short* t6  = allocH(SZ32);
    unsigned short* t7  = allocH(SZ32);

    Level L[4];
    const int*   eis[4] = {ei1, ei2, ei3, ei4};
    const float* us [4] = {u1, u2, u3, u4};
    const int    Es [4] = {E1, E2, E3, E4};
    const int    Ns [4] = {N1, N2, N3, N4};
    for (int l = 0; l < 4; ++l) {
        L[l].ei = eis[l]; L[l].u = us[l]; L[l].E = Es[l];
        L[l].maxchunks = (Es[l] + CHUNK - 1) / CHUNK + 64;
        // hist(64) + cursor(64) + deg(N) contiguous -> one memset
        int* blk = allocI(128 + Ns[l]);
        L[l].hist = blk; L[l].cursor = blk + 64; L[l].deg = (float*)(blk + 128);
        L[l].ek0     = allocI(Es[l]);
        L[l].bchunk0 = allocI(65);
        L[l].ck0     = allocI(L[l].maxchunks);
        L[l].ccnt    = allocI(L[l].maxchunks);
        L[l].perm    = allocI((size_t)L[l].maxchunks * CHUNK);
    }

    // ---- weight conversion (one launch, 10 banks) ----
    WtDescs wd;
    wd.d[0] = {w12, t12, 64, 64, 64};
    wd.d[1] = {w22, t22, 64, 64, 64};
    wd.d[2] = {w32, t32, 64, 64, 64};
    wd.d[3] = {w42, t42, 64, 64, 64};
    wd.d[4] = {w2,  t2,  64, 65, 64};
    wd.d[5] = {w3,  t3,  64, 65, 64};
    wd.d[6] = {w4,  t4,  64, 65, 64};
    wd.d[7] = {w5,  t5,  32, 32, 32};
    wd.d[8] = {w6,  t6,  32, 32, 32};
    wd.d[9] = {w7,  t7,  32, 32, 32};
    {
        dim3 g((125 * 64 * 64 + 255) / 256, 10);
        convert_wt<<<g, 256, 0, stream>>>(wd);
    }

    // ---- preprocessing: bucket-sort + degree per level ----
    for (int l = 0; l < 4; ++l) {
        (void)hipMemsetAsync(L[l].hist, 0, (128 + Ns[l]) * 4, stream);
        const int E = L[l].E;
        prep_k0_hist_deg<<<(E + 255) / 256, 256, 0, stream>>>(
            L[l].u, L[l].ei, E, L[l].ek0, L[l].hist, L[l].deg);
        scan64<<<1, 64, 0, stream>>>(L[l].hist, L[l].bchunk0);
        fill_chunks<<<(L[l].maxchunks + 255) / 256, 256, 0, stream>>>(
            L[l].bchunk0, L[l].hist, L[l].ck0, L[l].ccnt, L[l].maxchunks);
        scatter_perm<<<(E + 255) / 256, 256, 0, stream>>>(
            L[l].ek0, E, L[l].bchunk0, L[l].cursor, L[l].perm);
    }

    // ---- Level 1 ----
    // conv1: CIN=1 fp32 path
    (void)hipMemsetAsync(agg, 0, (size_t)N1 * 64 * sizeof(float), stream);
    bucket_edge<1, 64, 512><<<L[0].maxchunks, 512, 0, stream>>>(
        x, L[0].ei, L[0].u, w1, L[0].perm, L[0].ck0, L[0].ccnt, agg, L[0].E);
    spline_node<1, 64><<<(N1 + 3) / 4, 256, 0, stream>>>(x, agg, L[0].deg, r1, b1, h1a, N1);

    run_gemm_conv<64, 64, false>(stream, h1a, t12, nullptr, r12, b12, N1, h1, agg, L[0]);

    fill_pool<<<(N2 * 65 + 255) / 256, 256, 0, stream>>>(h2in, N2, 64);
    segmax<<<(N1 * 64 + 255) / 256, 256, 0, stream>>>(h1, c1, h2in, N1, 64, 65);

    // ---- Level 2 ----
    run_gemm_conv<64, 64, true >(stream, h2in, t2,  w2,  r2,  b2,  N2, h2a, agg, L[1]);
    run_gemm_conv<64, 64, false>(stream, h2a,  t22, nullptr, r22, b22, N2, h2, agg, L[1]);

    fill_pool<<<(N3 * 65 + 255) / 256, 256, 0, stream>>>(h3in, N3, 64);
    segmax<<<(N2 * 64 + 255) / 256, 256, 0, stream>>>(h2, c2, h3in, N2, 64, 65);

    // ---- Level 3 ----
    run_gemm_conv<64, 64, true >(stream, h3in, t3,  w3,  r3,  b3,  N3, h3a, agg, L[2]);
    run_gemm_conv<64, 64, false>(stream, h3a,  t32, nullptr, r32, b32, N3, h3, agg, L[2]);

    fill_pool<<<(N4 * 65 + 255) / 256, 256, 0, stream>>>(h4in, N4, 64);
    segmax<<<(N3 * 64 + 255) / 256, 256, 0, stream>>>(h3, c3, h4in, N3, 64, 65);

    // ---- Level 4 ----
    run_gemm_conv<64, 64, true >(stream, h4in, t4,  w4,  r4,  b4,  N4, h4a, agg, L[3]);
    run_gemm_conv<64, 64, false>(stream, h4a,  t42, nullptr, r42, b42, N4, h4b, agg, L[3]);
    run_gemm_conv<64, 64, false>(stream, h4b,  t42, nullptr, r42, b42, N4, h4c, agg, L[3]);

    linear_elu_64_32<<<(N4 + 7) / 8, 256, 0, stream>>>(h4c, fc1w, fc1b, h4, N4);

    // ---- Decoder ----
    skip_gather<<<(N3 + 7) / 8, 256, 0, stream>>>(h4, c3, h3, sk3w, sk3b, g3in, N3);
    run_gemm_conv<32, 32, false>(stream, g3in, t5, nullptr, r5, b5, N3, g3, agg, L[2]);

    skip_gather<<<(N2 + 7) / 8, 256, 0, stream>>>(g3, c2, h2, sk2w, sk2b, g2in, N2);
    run_gemm_conv<32, 32, false>(stream, g2in, t6, nullptr, r6, b6, N2, g2, agg, L[1]);

    skip_gather<<<(N1 + 7) / 8, 256, 0, stream>>>(g2, c1, h1, sk1w, sk1b, g1in, N1);
    run_gemm_conv<32, 32, false>(stream, g1in, t7, nullptr, r7, b7, N1, g1, agg, L[0]);

    // ---- Head ----
    final_logsoftmax<<<(N1 + 255) / 256, 256, 0, stream>>>(g1, fc2w, fc2b, out, N1);
}

// Round 5
// 294.571 us; speedup vs baseline: 4.3577x; 1.2432x over previous
//
#include <hip/hip_runtime.h>
#include <math.h>

// ---------------------------------------------------------------------------
// SplineCNN forward. Edge message GEMMs in bf16 MFMA (fp32 accumulate),
// everything else fp32. k0-bucketed edges (device count-sort, one per level).
// Round 4: dispatch-count reduction via fusion (33 dispatches total).
// ---------------------------------------------------------------------------

static const int N1 = 10000, E1 = 60000;
static const int N2 = 2500,  E2 = 15000;
static const int N3 = 625,   E3 = 3750;
static const int N4 = 160,   E4 = 960;
static const int NC = 4;
static const int CHUNK = 64;

typedef __attribute__((ext_vector_type(8))) short bfrag;
typedef __attribute__((ext_vector_type(4))) float f32x4;

__device__ __forceinline__ float eluf(float x) { return x > 0.f ? x : expm1f(x); }

__device__ __forceinline__ unsigned short bfc(float f) {   // f32 -> bf16 RNE
    unsigned u = __float_as_uint(f);
    return (unsigned short)((u + 0x7FFF + ((u >> 16) & 1)) >> 16);
}

// ---------------------------------------------------------------------------
// init_misc: one dispatch doing (A) W->bf16 packed conversion for 10 banks,
// (B) pool prefill (-inf / ones col), (C) agg zero, (D) hist/cursor/deg zero.
// ---------------------------------------------------------------------------
struct InitArgs {
    const float* wsrc[10]; unsigned short* wdst[10];
    int cinmat[10], xs_[10], cout[10];
    long welems[10];            // cumulative elem end-offsets
    long wtot;
    float* pools[3]; int pM[3]; // cumulative elem end-offsets (M*65)
    float* agg; int aggN4;      // float4 count
    int* preblk; int preN;
    int bB, bC, bD;             // block-range starts for roles B, C, D
};

__global__ __launch_bounds__(256) void init_misc(InitArgs A) {
    const int blk = blockIdx.x, tid = threadIdx.x;
    if (blk < A.bB) {                       // role A: weight conversion
        const long t = (long)blk * 256 + tid;
        if (t >= A.wtot) return;
        int k = 0;
        while (t >= A.welems[k]) ++k;
        const long base = k ? A.welems[k - 1] : 0;
        const long i2 = t - base;
        const int co = A.cout[k], cm = A.cinmat[k], xs = A.xs_[k];
        const int o = (int)(i2 % co);
        const long rest = i2 / co;
        const int i = (int)(rest % cm);
        const int kk = (int)(rest / cm);
        const float v = A.wsrc[k][((size_t)kk * xs + i) * co + o];
        const int KG = cm >> 3;
        A.wdst[k][(((size_t)(kk * KG + (i >> 3))) * co + o) * 8 + (i & 7)] = bfc(v);
    } else if (blk < A.bC) {                // role B: pool prefill
        const int t = (blk - A.bB) * 256 + tid;
        if (t >= A.pM[2]) return;
        const int p = (t < A.pM[0]) ? 0 : (t < A.pM[1] ? 1 : 2);
        const int base = p ? A.pM[p - 1] : 0;
        const int i2 = t - base;
        A.pools[p][i2] = (i2 % 65 == 64) ? 1.0f : -INFINITY;
    } else if (blk < A.bD) {                // role C: agg zero
        const int t = (blk - A.bC) * 256 + tid;
        if (t < A.aggN4) ((float4*)A.agg)[t] = make_float4(0.f, 0.f, 0.f, 0.f);
    } else {                                // role D: preblk zero
        const int t = (blk - A.bD) * 256 + tid;
        if (t < A.preN) A.preblk[t] = 0;
    }
}

// ---------------------------------------------------------------------------
// Batched preprocessing over all 4 levels.
// ---------------------------------------------------------------------------
struct Levels {
    const float* u[4]; const int* ei[4]; int E[4];
    int nb0[5];   // cumulative 256-edge block offsets
    int cb0[5];   // cumulative fill_chunks block offsets
    int mc[4];    // maxchunks per level
    int* ek0[4]; int* hist[4]; int* cursor[4]; float* deg[4];
    int* bchunk0[4]; int* ck0[4]; int* ccnt[4]; int* perm[4];
};

__global__ __launch_bounds__(256) void prep_all(Levels L) {
    int l = 0;
    while (l < 3 && (int)blockIdx.x >= L.nb0[l + 1]) ++l;
    const int bl = blockIdx.x - L.nb0[l];
    __shared__ int lh[64];
    const int t = threadIdx.x;
    if (t < 64) lh[t] = 0;
    __syncthreads();
    const int e = bl * 256 + t;
    if (e < L.E[l]) {
        int b = 0;
        #pragma unroll
        for (int d = 0; d < 3; ++d) {
            const float v = L.u[l][e * 3 + d] * 4.0f;
            const float kf = fminf(fmaxf(floorf(v), 0.f), 3.f);
            b = (b << 2) | (int)kf;
        }
        L.ek0[l][e] = b;
        atomicAdd(&lh[b], 1);
        atomicAdd(&L.deg[l][L.ei[l][L.E[l] + e]], 1.0f);
    }
    __syncthreads();
    if (t < 64 && lh[t]) atomicAdd(&L.hist[l][t], lh[t]);
}

__global__ void scan_all(Levels L) {
    const int l = blockIdx.x;     // 4 blocks x 64 threads
    __shared__ int sb[65];
    const int t = threadIdx.x;
    if (t == 0) {
        int cc = 0;
        for (int b = 0; b < 64; ++b) { sb[b] = cc; cc += (L.hist[l][b] + CHUNK - 1) / CHUNK; }
        sb[64] = cc;
    }
    __syncthreads();
    L.bchunk0[l][t] = sb[t];
    if (t == 0) L.bchunk0[l][64] = sb[64];
}

__global__ void fill_chunks_all(Levels L) {
    int l = 0;
    while (l < 3 && (int)blockIdx.x >= L.cb0[l + 1]) ++l;
    const int c = (blockIdx.x - L.cb0[l]) * 256 + threadIdx.x;
    if (c >= L.mc[l]) return;
    const int* bchunk0 = L.bchunk0[l];
    if (c >= bchunk0[64]) { L.ccnt[l][c] = 0; L.ck0[l][c] = 0; return; }
    int lo = 0, hi = 64;
    while (hi - lo > 1) { int m = (lo + hi) >> 1; if (bchunk0[m] <= c) lo = m; else hi = m; }
    const int j = c - bchunk0[lo];
    L.ck0[l][c] = lo;
    L.ccnt[l][c] = min(CHUNK, L.hist[l][lo] - j * CHUNK);
}

__global__ __launch_bounds__(256) void scatter_all(Levels L) {
    int l = 0;
    while (l < 3 && (int)blockIdx.x >= L.nb0[l + 1]) ++l;
    const int bl = blockIdx.x - L.nb0[l];
    __shared__ int lh[64], lbase[64];
    const int t = threadIdx.x;
    if (t < 64) lh[t] = 0;
    __syncthreads();
    const int e = bl * 256 + t;
    int b = -1, r = 0;
    if (e < L.E[l]) { b = L.ek0[l][e]; r = atomicAdd(&lh[b], 1); }
    __syncthreads();
    if (t < 64) lbase[t] = lh[t] ? atomicAdd(&L.cursor[l][t], lh[t]) : 0;
    __syncthreads();
    if (e < L.E[l]) L.perm[l][L.bchunk0[l][b] * CHUNK + lbase[b] + r] = e;
}

// ---------------------------------------------------------------------------
// MFMA bucket-GEMM edge kernel.
// ---------------------------------------------------------------------------
template<int CINMAT, int COUT, bool HAS_ONES>
__global__ __launch_bounds__(256) void bucket_gemm(
        const float* __restrict__ x, const int* __restrict__ ei, const float* __restrict__ u,
        const unsigned short* __restrict__ Wt, const float* __restrict__ Wf,
        const int* __restrict__ perm, const int* __restrict__ ck0, const int* __restrict__ ccnt,
        float* __restrict__ agg, int E) {
    constexpr int ALDA = CINMAT + 8;
    constexpr int KG   = CINMAT / 8;
    constexpr int NT   = COUT / 16;
    constexpr int HALVES = CINMAT / 32;
    constexpr int XS   = CINMAT + (HAS_ONES ? 1 : 0);
    constexpr int IT   = CINMAT / 4;

    __shared__ unsigned short A0s[64 * ALDA], A1s[64 * ALDA];
    __shared__ float gS[64 * 4], sS[64 * 2];
    __shared__ int srcS[64], dstS[64];
    __shared__ float WonesS[HAS_ONES ? 8 * COUT : 4];

    const int chunk = blockIdx.x;
    const int cnt = ccnt[chunk];
    if (cnt == 0) return;
    const int b = ck0[chunk];
    const int kbase = ((b >> 4) & 3) * 25 + ((b >> 2) & 3) * 5 + (b & 3);
    const int cstart = chunk * CHUNK;
    const int tid = threadIdx.x;

    if (tid < CHUNK) {
        const int e = tid;
        const int pe = (e < cnt) ? perm[cstart + e] : -1;
        int sv = -1, dv = 0;
        float g0 = 0, g1 = 0, g2 = 0, g3 = 0, s0 = 0, s1 = 0;
        if (pe >= 0) {
            sv = ei[pe]; dv = ei[E + pe];
            float f[3];
            #pragma unroll
            for (int d2 = 0; d2 < 3; ++d2) {
                const float v = u[pe * 3 + d2] * 4.f;
                const float kf = fminf(fmaxf(floorf(v), 0.f), 3.f);
                f[d2] = v - kf;
            }
            g0 = (1.f - f[0]) * (1.f - f[1]); g1 = (1.f - f[0]) * f[1];
            g2 = f[0] * (1.f - f[1]);         g3 = f[0] * f[1];
            s0 = 1.f - f[2]; s1 = f[2];
        }
        srcS[e] = sv; dstS[e] = dv;
        gS[e * 4 + 0] = g0; gS[e * 4 + 1] = g1; gS[e * 4 + 2] = g2; gS[e * 4 + 3] = g3;
        sS[e * 2 + 0] = s0; sS[e * 2 + 1] = s1;
    }
    if (HAS_ONES) {
        for (int t2 = tid; t2 < 8 * COUT; t2 += 256) {
            const int c = t2 / COUT, o = t2 % COUT;
            const int koff = ((c >> 2) & 1) * 25 + ((c >> 1) & 1) * 5 + (c & 1);
            WonesS[t2] = Wf[((size_t)(kbase + koff) * XS + CINMAT) * COUT + o];
        }
    }
    __syncthreads();

    {
        const int e  = tid >> 2;
        const int ib = (tid & 3) * IT;
        const int sv = srcS[e];
        const float sc0 = sS[e * 2], sc1 = sS[e * 2 + 1];
        #pragma unroll
        for (int j = 0; j < IT; j += 2) {
            float x0 = 0.f, x1 = 0.f;
            if (sv >= 0) {
                x0 = x[(size_t)sv * XS + ib + j];
                x1 = x[(size_t)sv * XS + ib + j + 1];
            }
            const unsigned p0 = bfc(x0 * sc0) | ((unsigned)bfc(x1 * sc0) << 16);
            const unsigned p1 = bfc(x0 * sc1) | ((unsigned)bfc(x1 * sc1) << 16);
            *(unsigned*)&A0s[e * ALDA + ib + j] = p0;
            *(unsigned*)&A1s[e * ALDA + ib + j] = p1;
        }
    }
    __syncthreads();

    const int lane = tid & 63;
    const int wid  = tid >> 6;
    const int m0   = wid * 16;
    const int arow = m0 + (lane & 15);
    const int kg   = lane >> 4;
    const int ocol = lane & 15;

    f32x4 acc[4][NT];
    #pragma unroll
    for (int q = 0; q < 4; ++q)
        #pragma unroll
        for (int nt = 0; nt < NT; ++nt) acc[q][nt] = (f32x4){0.f, 0.f, 0.f, 0.f};

    #pragma unroll
    for (int q = 0; q < 4; ++q) {
        #pragma unroll
        for (int b2 = 0; b2 < 2; ++b2) {
            const unsigned short* Ab = b2 ? A1s : A0s;
            const int koff = (q >> 1) * 25 + (q & 1) * 5 + b2;
            #pragma unroll
            for (int hf = 0; hf < HALVES; ++hf) {
                const bfrag a = *(const bfrag*)(Ab + arow * ALDA + hf * 32 + kg * 8);
                const int krow = (kbase + koff) * KG + hf * 4 + kg;
                #pragma unroll
                for (int nt = 0; nt < NT; ++nt) {
                    const bfrag bb = *(const bfrag*)(Wt + ((size_t)krow * COUT + nt * 16 + ocol) * 8);
                    acc[q][nt] = __builtin_amdgcn_mfma_f32_16x16x32_bf16(a, bb, acc[q][nt], 0, 0, 0);
                }
            }
        }
    }

    const int grp = lane >> 4;
    #pragma unroll
    for (int nt = 0; nt < NT; ++nt) {
        const int o = nt * 16 + ocol;
        float wo[8];
        if (HAS_ONES) {
            #pragma unroll
            for (int c = 0; c < 8; ++c) wo[c] = WonesS[c * COUT + o];
        }
        #pragma unroll
        for (int r = 0; r < 4; ++r) {
            const int e = m0 + grp * 4 + r;
            if (e < cnt) {
                const float g0 = gS[e * 4 + 0], g1 = gS[e * 4 + 1];
                const float g2 = gS[e * 4 + 2], g3 = gS[e * 4 + 3];
                float v = g0 * acc[0][nt][r] + g1 * acc[1][nt][r] +
                          g2 * acc[2][nt][r] + g3 * acc[3][nt][r];
                if (HAS_ONES) {
                    const float s0v = sS[e * 2], s1v = sS[e * 2 + 1];
                    v += g0 * (s0v * wo[0] + s1v * wo[1]) + g1 * (s0v * wo[2] + s1v * wo[3]) +
                         g2 * (s0v * wo[4] + s1v * wo[5]) + g3 * (s0v * wo[6] + s1v * wo[7]);
                }
                atomicAdd(&agg[(size_t)dstS[e] * COUT + o], v);
            }
        }
    }
}

// ---------------------------------------------------------------------------
// conv1 (CIN=1) fp32 edge kernel
// ---------------------------------------------------------------------------
template<int CIN, int COUT, int BLK>
__global__ __launch_bounds__(BLK) void bucket_edge(
        const float* __restrict__ x, const int* __restrict__ ei, const float* __restrict__ u,
        const float* __restrict__ W, const int* __restrict__ perm,
        const int* __restrict__ ck0, const int* __restrict__ ccnt,
        float* __restrict__ agg, int E) {
    constexpr int CINP = (CIN + 3) & ~3;
    __shared__ float xs[CHUNK * CINP];
    __shared__ float wgt[CHUNK * 8];
    __shared__ int pel[CHUNK], srcl[CHUNK], dstl[CHUNK];

    const int chunk = blockIdx.x;
    const int cnt = ccnt[chunk];
    if (cnt == 0) return;
    const int b = ck0[chunk];
    const int kbase = ((b >> 4) & 3) * 25 + ((b >> 2) & 3) * 5 + (b & 3);
    const int cstart = chunk * CHUNK;
    const int tid = threadIdx.x;

    for (int e = tid; e < CHUNK; e += BLK) {
        if (e < cnt) {
            const int pe = perm[cstart + e];
            pel[e] = pe; srcl[e] = ei[pe]; dstl[e] = ei[E + pe];
        } else { pel[e] = -1; srcl[e] = -1; dstl[e] = -1; }
    }
    __syncthreads();
    for (int t2 = tid; t2 < CHUNK * 8; t2 += BLK) {
        const int e = t2 >> 3, c = t2 & 7;
        float w = 0.f;
        const int pe = pel[e];
        if (pe >= 0) {
            w = 1.f;
            #pragma unroll
            for (int d = 0; d < 3; ++d) {
                const float v = u[pe * 3 + d] * 4.0f;
                const float kf = fminf(fmaxf(floorf(v), 0.f), 3.f);
                const float fr = v - kf;
                const int bd = (c >> (2 - d)) & 1;
                w *= bd ? fr : 1.f - fr;
            }
        }
        wgt[t2] = w;
    }
    for (int t2 = tid; t2 < CHUNK * CINP; t2 += BLK) {
        const int e = t2 / CINP, i = t2 - e * CINP;
        const int s = srcl[e];
        xs[t2] = (s >= 0 && i < CIN) ? x[(size_t)s * CIN + i] : 0.f;
    }
    __syncthreads();

    const int lane = tid & 63;
    const int wid  = tid >> 6;
    const int o = lane;
    const int ehbase = wid * 8;

    float acc2[8][8];
    #pragma unroll
    for (int c = 0; c < 8; ++c)
        #pragma unroll
        for (int e = 0; e < 8; ++e) acc2[c][e] = 0.f;

    for (int i = 0; i < CIN; ++i) {
        float xr1[8];
        #pragma unroll
        for (int e = 0; e < 8; ++e) xr1[e] = xs[(ehbase + e) * CINP + i];
        #pragma unroll
        for (int c = 0; c < 8; ++c) {
            const int off = ((c >> 2) & 1) * 25 + ((c >> 1) & 1) * 5 + (c & 1);
            const float w0 = W[(size_t)(kbase + off) * (CIN * COUT) + (size_t)i * COUT + o];
            #pragma unroll
            for (int e = 0; e < 8; ++e) acc2[c][e] += xr1[e] * w0;
        }
    }
    #pragma unroll
    for (int e = 0; e < 8; ++e) {
        const int ge = ehbase + e;
        if (ge < cnt) {
            float a = 0.f;
            #pragma unroll
            for (int c = 0; c < 8; ++c) a += wgt[ge * 8 + c] * acc2[c][e];
            atomicAdd(&agg[(size_t)dstl[ge] * COUT + o], a);
        }
    }
}

// ---------------------------------------------------------------------------
// Fused node kernel. MODE: 0 plain, 1 +segmax into pool, 2 +log_softmax head.
// Always zeroes agg after reading (replaces per-conv memset).
// ---------------------------------------------------------------------------
enum { NODE_PLAIN = 0, NODE_SEGMAX = 1, NODE_LSM = 2 };

template<int CIN, int COUT, int MODE>
__global__ void spline_node_f(const float* __restrict__ x, float* __restrict__ agg,
                              const float* __restrict__ deg, const float* __restrict__ R,
                              const float* __restrict__ b, float* __restrict__ out, int N,
                              const int* __restrict__ cl, float* __restrict__ pool,
                              const float* __restrict__ fcw, const float* __restrict__ fcb,
                              float* __restrict__ lout) {
    constexpr int NPB = 256 / COUT;
    const int lane = threadIdx.x % COUT;
    const int grp  = threadIdx.x / COUT;
    const int n = blockIdx.x * NPB + grp;
    if (n >= N) return;
    const float d = fmaxf(deg[n], 1.f);
    const size_t idx = (size_t)n * COUT + lane;
    float s = agg[idx] / d + b[lane];
    agg[idx] = 0.f;                 // reset for the next conv's atomics
    const float* xs = x + (size_t)n * CIN;
    #pragma unroll 4
    for (int i = 0; i < CIN; ++i) s += xs[i] * R[i * COUT + lane];
    const float val = eluf(s);
    if (MODE != NODE_LSM) out[idx] = val;
    if (MODE == NODE_SEGMAX) {
        float* addr = pool + (size_t)cl[n] * 65 + lane;
        if (val >= 0.f) atomicMax((int*)addr, __float_as_int(val));
        else            atomicMin((unsigned int*)addr, __float_as_uint(val));
    }
    if (MODE == NODE_LSM) {         // COUT == 32: logits + log_softmax
        float p[NC];
        #pragma unroll
        for (int o = 0; o < NC; ++o) p[o] = val * fcw[lane * NC + o];
        #pragma unroll
        for (int m = 16; m >= 1; m >>= 1)
            #pragma unroll
            for (int o = 0; o < NC; ++o) p[o] += __shfl_xor(p[o], m, 32);
        #pragma unroll
        for (int o = 0; o < NC; ++o) p[o] += fcb[o];
        const float mx = fmaxf(fmaxf(p[0], p[1]), fmaxf(p[2], p[3]));
        float se = 0.f;
        #pragma unroll
        for (int o = 0; o < NC; ++o) se += expf(p[o] - mx);
        const float lg = logf(se);
        if (lane < NC) lout[(size_t)n * NC + lane] = p[lane] - mx - lg;
    }
}

__global__ void skip_gather(const float* __restrict__ up, const int* __restrict__ cl,
                            const float* __restrict__ h, const float* __restrict__ skw,
                            const float* __restrict__ skb, float* __restrict__ out, int N) {
    const int lane = threadIdx.x & 31;
    const int grp  = threadIdx.x >> 5;
    const int n = blockIdx.x * 8 + grp;
    if (n >= N) return;
    float s = up[(size_t)cl[n] * 32 + lane] + skb[lane];
    const float* hs = h + (size_t)n * 64;
    #pragma unroll 4
    for (int i = 0; i < 64; ++i) s += hs[i] * skw[i * 32 + lane];
    out[(size_t)n * 32 + lane] = s;
}

__global__ void linear_elu_64_32(const float* __restrict__ x, const float* __restrict__ w,
                                 const float* __restrict__ b, float* __restrict__ out, int N) {
    const int lane = threadIdx.x & 31;
    const int grp  = threadIdx.x >> 5;
    const int n = blockIdx.x * 8 + grp;
    if (n >= N) return;
    float s = b[lane];
    const float* xs = x + (size_t)n * 64;
    #pragma unroll 4
    for (int i = 0; i < 64; ++i) s += xs[i] * w[i * 32 + lane];
    out[(size_t)n * 32 + lane] = eluf(s);
}

// ---------------------------------------------------------------------------
// Host orchestration
// ---------------------------------------------------------------------------
struct HLevel {
    const int* ei; const float* u; int E; int maxchunks;
    int *ek0, *hist, *cursor, *bchunk0, *ck0, *ccnt, *perm;
    float* deg;
};

extern "C" void kernel_launch(void* const* d_in, const int* in_sizes, int n_in,
                              void* d_out, int out_size, void* d_ws, size_t ws_size,
                              hipStream_t stream) {
    const float* x    = (const float*)d_in[0];
    const int*   ei1  = (const int*)  d_in[1];
    const float* u1   = (const float*)d_in[2];
    const int*   ei2  = (const int*)  d_in[3];
    const float* u2   = (const float*)d_in[4];
    const int*   ei3  = (const int*)  d_in[5];
    const float* u3   = (const float*)d_in[6];
    const int*   ei4  = (const int*)  d_in[7];
    const float* u4   = (const float*)d_in[8];
    const int*   c1   = (const int*)  d_in[9];
    const int*   c2   = (const int*)  d_in[10];
    const int*   c3   = (const int*)  d_in[11];
    const float *w1  = (const float*)d_in[12], *r1  = (const float*)d_in[13], *b1  = (const float*)d_in[14];
    const float *w12 = (const float*)d_in[15], *r12 = (const float*)d_in[16], *b12 = (const float*)d_in[17];
    const float *w2  = (const float*)d_in[18], *r2  = (const float*)d_in[19], *b2  = (const float*)d_in[20];
    const float *w22 = (const float*)d_in[21], *r22 = (const float*)d_in[22], *b22 = (const float*)d_in[23];
    const float *w3  = (const float*)d_in[24], *r3  = (const float*)d_in[25], *b3  = (const float*)d_in[26];
    const float *w32 = (const float*)d_in[27], *r32 = (const float*)d_in[28], *b32 = (const float*)d_in[29];
    const float *w4  = (const float*)d_in[30], *r4  = (const float*)d_in[31], *b4  = (const float*)d_in[32];
    const float *w42 = (const float*)d_in[33], *r42 = (const float*)d_in[34], *b42 = (const float*)d_in[35];
    const float *w5  = (const float*)d_in[36], *r5  = (const float*)d_in[37], *b5  = (const float*)d_in[38];
    const float *w6  = (const float*)d_in[39], *r6  = (const float*)d_in[40], *b6  = (const float*)d_in[41];
    const float *w7  = (const float*)d_in[42], *r7  = (const float*)d_in[43], *b7  = (const float*)d_in[44];
    const float *fc1w = (const float*)d_in[45], *fc1b = (const float*)d_in[46];
    const float *fc2w = (const float*)d_in[47], *fc2b = (const float*)d_in[48];
    const float *sk1w = (const float*)d_in[49], *sk1b = (const float*)d_in[50];
    const float *sk2w = (const float*)d_in[51], *sk2b = (const float*)d_in[52];
    const float *sk3w = (const float*)d_in[53], *sk3b = (const float*)d_in[54];
    float* out = (float*)d_out;

    char* wsb = (char*)d_ws;
    size_t off = 0;
    auto alloc = [&](size_t bytes) {
        void* p = wsb + off; off = (off + bytes + 255) & ~(size_t)255; return p;
    };
    auto allocF = [&](size_t n) { return (float*)alloc(n * 4); };
    auto allocI = [&](size_t n) { return (int*)alloc(n * 4); };
    auto allocH = [&](size_t n) { return (unsigned short*)alloc(n * 2); };

    float* h1a  = allocF((size_t)N1 * 64);
    float* h1   = allocF((size_t)N1 * 64);
    float* h2in = allocF((size_t)N2 * 65);
    float* h2a  = allocF((size_t)N2 * 64);
    float* h2   = allocF((size_t)N2 * 64);
    float* h3in = allocF((size_t)N3 * 65);
    float* h3a  = allocF((size_t)N3 * 64);
    float* h3   = allocF((size_t)N3 * 64);
    float* h4in = allocF((size_t)N4 * 65);
    float* h4a  = allocF((size_t)N4 * 64);
    float* h4b  = allocF((size_t)N4 * 64);
    float* h4c  = allocF((size_t)N4 * 64);
    float* h4   = allocF((size_t)N4 * 32);
    float* g3in = allocF((size_t)N3 * 32);
    float* g3   = allocF((size_t)N3 * 32);
    float* g2in = allocF((size_t)N2 * 32);
    float* g2   = allocF((size_t)N2 * 32);
    float* g1in = allocF((size_t)N1 * 32);
    float* agg  = allocF((size_t)N1 * 64);

    const size_t SZ64 = (size_t)125 * 8 * 64 * 8;
    const size_t SZ32 = (size_t)125 * 4 * 32 * 8;
    unsigned short* t12 = allocH(SZ64);
    unsigned short* t22 = allocH(SZ64);
    unsigned short* t32 = allocH(SZ64);
    unsigned short* t42 = allocH(SZ64);
    unsigned short* t2  = allocH(SZ64);
    unsigned short* t3  = allocH(SZ64);
    unsigned short* t4  = allocH(SZ64);
    unsigned short* t5  = allocH(SZ32);
    unsigned short* t6  = allocH(SZ32);
    unsigned short* t7  = allocH(SZ32);

    HLevel L[4];
    const int*   eis[4] = {ei1, ei2, ei3, ei4};
    const float* us [4] = {u1, u2, u3, u4};
    const int    Es [4] = {E1, E2, E3, E4};
    const int    Ns [4] = {N1, N2, N3, N4};

    // one contiguous preblk: per level [hist(64) | cursor(64) | deg(N)]
    int preN = 0;
    for (int l = 0; l < 4; ++l) preN += 128 + Ns[l];
    int* preblk = allocI(preN);
    {
        int c = 0;
        for (int l = 0; l < 4; ++l) {
            L[l].ei = eis[l]; L[l].u = us[l]; L[l].E = Es[l];
            L[l].maxchunks = (Es[l] + CHUNK - 1) / CHUNK + 64;
            L[l].hist = preblk + c; L[l].cursor = preblk + c + 64;
            L[l].deg = (float*)(preblk + c + 128);
            c += 128 + Ns[l];
            L[l].ek0     = allocI(Es[l]);
            L[l].bchunk0 = allocI(65);
            L[l].ck0     = allocI(L[l].maxchunks);
            L[l].ccnt    = allocI(L[l].maxchunks);
            L[l].perm    = allocI((size_t)L[l].maxchunks * CHUNK);
        }
    }

    // ---- dispatch 1: init_misc ----
    InitArgs IA;
    {
        const float* srcs[10] = {w12, w22, w32, w42, w2, w3, w4, w5, w6, w7};
        unsigned short* dsts[10] = {t12, t22, t32, t42, t2, t3, t4, t5, t6, t7};
        const int cms[10] = {64,64,64,64,64,64,64,32,32,32};
        const int xss[10] = {64,64,64,64,65,65,65,32,32,32};
        const int cos[10] = {64,64,64,64,64,64,64,32,32,32};
        long cum = 0;
        for (int k = 0; k < 10; ++k) {
            IA.wsrc[k] = srcs[k]; IA.wdst[k] = dsts[k];
            IA.cinmat[k] = cms[k]; IA.xs_[k] = xss[k]; IA.cout[k] = cos[k];
            cum += (long)125 * cms[k] * cos[k];
            IA.welems[k] = cum;
        }
        IA.wtot = cum;
        IA.pools[0] = h2in; IA.pools[1] = h3in; IA.pools[2] = h4in;
        IA.pM[0] = N2 * 65; IA.pM[1] = N2 * 65 + N3 * 65; IA.pM[2] = N2 * 65 + N3 * 65 + N4 * 65;
        IA.agg = agg; IA.aggN4 = N1 * 64 / 4;
        IA.preblk = preblk; IA.preN = preN;
        const int bA = (int)((IA.wtot + 255) / 256);
        const int bB = (IA.pM[2] + 255) / 256;
        const int bC = (IA.aggN4 + 255) / 256;
        const int bD = (preN + 255) / 256;
        IA.bB = bA; IA.bC = bA + bB; IA.bD = bA + bB + bC;
        init_misc<<<bA + bB + bC + bD, 256, 0, stream>>>(IA);
    }

    // ---- dispatches 2-5: batched preprocessing ----
    Levels DL;
    {
        int nb = 0, cb = 0;
        for (int l = 0; l < 4; ++l) {
            DL.u[l] = L[l].u; DL.ei[l] = L[l].ei; DL.E[l] = L[l].E;
            DL.nb0[l] = nb; nb += (L[l].E + 255) / 256;
            DL.cb0[l] = cb; cb += (L[l].maxchunks + 255) / 256;
            DL.mc[l] = L[l].maxchunks;
            DL.ek0[l] = L[l].ek0; DL.hist[l] = L[l].hist; DL.cursor[l] = L[l].cursor;
            DL.deg[l] = L[l].deg; DL.bchunk0[l] = L[l].bchunk0;
            DL.ck0[l] = L[l].ck0; DL.ccnt[l] = L[l].ccnt; DL.perm[l] = L[l].perm;
        }
        DL.nb0[4] = nb; DL.cb0[4] = cb;
        prep_all<<<nb, 256, 0, stream>>>(DL);
        scan_all<<<4, 64, 0, stream>>>(DL);
        fill_chunks_all<<<cb, 256, 0, stream>>>(DL);
        scatter_all<<<nb, 256, 0, stream>>>(DL);
    }

    // ---- Level 1 ----
    bucket_edge<1, 64, 512><<<L[0].maxchunks, 512, 0, stream>>>(
        x, L[0].ei, L[0].u, w1, L[0].perm, L[0].ck0, L[0].ccnt, agg, L[0].E);
    spline_node_f<1, 64, NODE_PLAIN><<<(N1 + 3) / 4, 256, 0, stream>>>(
        x, agg, L[0].deg, r1, b1, h1a, N1, nullptr, nullptr, nullptr, nullptr, nullptr);

    bucket_gemm<64, 64, false><<<L[0].maxchunks, 256, 0, stream>>>(
        h1a, L[0].ei, L[0].u, t12, nullptr, L[0].perm, L[0].ck0, L[0].ccnt, agg, L[0].E);
    spline_node_f<64, 64, NODE_SEGMAX><<<(N1 + 3) / 4, 256, 0, stream>>>(
        h1a, agg, L[0].deg, r12, b12, h1, N1, c1, h2in, nullptr, nullptr, nullptr);

    // ---- Level 2 ----
    bucket_gemm<64, 64, true><<<L[1].maxchunks, 256, 0, stream>>>(
        h2in, L[1].ei, L[1].u, t2, w2, L[1].perm, L[1].ck0, L[1].ccnt, agg, L[1].E);
    spline_node_f<65, 64, NODE_PLAIN><<<(N2 + 3) / 4, 256, 0, stream>>>(
        h2in, agg, L[1].deg, r2, b2, h2a, N2, nullptr, nullptr, nullptr, nullptr, nullptr);
    bucket_gemm<64, 64, false><<<L[1].maxchunks, 256, 0, stream>>>(
        h2a, L[1].ei, L[1].u, t22, nullptr, L[1].perm, L[1].ck0, L[1].ccnt, agg, L[1].E);
    spline_node_f<64, 64, NODE_SEGMAX><<<(N2 + 3) / 4, 256, 0, stream>>>(
        h2a, agg, L[1].deg, r22, b22, h2, N2, c2, h3in, nullptr, nullptr, nullptr);

    // ---- Level 3 ----
    bucket_gemm<64, 64, true><<<L[2].maxchunks, 256, 0, stream>>>(
        h3in, L[2].ei, L[2].u, t3, w3, L[2].perm, L[2].ck0, L[2].ccnt, agg, L[2].E);
    spline_node_f<65, 64, NODE_PLAIN><<<(N3 + 3) / 4, 256, 0, stream>>>(
        h3in, agg, L[2].deg, r3, b3, h3a, N3, nullptr, nullptr, nullptr, nullptr, nullptr);
    bucket_gemm<64, 64, false><<<L[2].maxchunks, 256, 0, stream>>>(
        h3a, L[2].ei, L[2].u, t32, nullptr, L[2].perm, L[2].ck0, L[2].ccnt, agg, L[2].E);
    spline_node_f<64, 64, NODE_SEGMAX><<<(N3 + 3) / 4, 256, 0, stream>>>(
        h3a, agg, L[2].deg, r32, b32, h3, N3, c3, h4in, nullptr, nullptr, nullptr);

    // ---- Level 4 ----
    bucket_gemm<64, 64, true><<<L[3].maxchunks, 256, 0, stream>>>(
        h4in, L[3].ei, L[3].u, t4, w4, L[3].perm, L[3].ck0, L[3].ccnt, agg, L[3].E);
    spline_node_f<65, 64, NODE_PLAIN><<<(N4 + 3) / 4, 256, 0, stream>>>(
        h4in, agg, L[3].deg, r4, b4, h4a, N4, nullptr, nullptr, nullptr, nullptr, nullptr);
    bucket_gemm<64, 64, false><<<L[3].maxchunks, 256, 0, stream>>>(
        h4a, L[3].ei, L[3].u, t42, nullptr, L[3].perm, L[3].ck0, L[3].ccnt, agg, L[3].E);
    spline_node_f<64, 64, NODE_PLAIN><<<(N4 + 3) / 4, 256, 0, stream>>>(
        h4a, agg, L[3].deg, r42, b42, h4b, N4, nullptr, nullptr, nullptr, nullptr, nullptr);
    bucket_gemm<64, 64, false><<<L[3].maxchunks, 256, 0, stream>>>(
        h4b, L[3].ei, L[3].u, t42, nullptr, L[3].perm, L[3].ck0, L[3].ccnt, agg, L[3].E);
    spline_node_f<64, 64, NODE_PLAIN><<<(N4 + 3) / 4, 256, 0, stream>>>(
        h4b, agg, L[3].deg, r42, b42, h4c, N4, nullptr, nullptr, nullptr, nullptr, nullptr);

    linear_elu_64_32<<<(N4 + 7) / 8, 256, 0, stream>>>(h4c, fc1w, fc1b, h4, N4);

    // ---- Decoder ----
    skip_gather<<<(N3 + 7) / 8, 256, 0, stream>>>(h4, c3, h3, sk3w, sk3b, g3in, N3);
    bucket_gemm<32, 32, false><<<L[2].maxchunks, 256, 0, stream>>>(
        g3in, L[2].ei, L[2].u, t5, nullptr, L[2].perm, L[2].ck0, L[2].ccnt, agg, L[2].E);
    spline_node_f<32, 32, NODE_PLAIN><<<(N3 + 7) / 8, 256, 0, stream>>>(
        g3in, agg, L[2].deg, r5, b5, g3, N3, nullptr, nullptr, nullptr, nullptr, nullptr);

    skip_gather<<<(N2 + 7) / 8, 256, 0, stream>>>(g3, c2, h2, sk2w, sk2b, g2in, N2);
    bucket_gemm<32, 32, false><<<L[1].maxchunks, 256, 0, stream>>>(
        g2in, L[1].ei, L[1].u, t6, nullptr, L[1].perm, L[1].ck0, L[1].ccnt, agg, L[1].E);
    spline_node_f<32, 32, NODE_PLAIN><<<(N2 + 7) / 8, 256, 0, stream>>>(
        g2in, agg, L[1].deg, r6, b6, g2, N2, nullptr, nullptr, nullptr, nullptr, nullptr);

    skip_gather<<<(N1 + 7) / 8, 256, 0, stream>>>(g2, c1, h1, sk1w, sk1b, g1in, N1);
    bucket_gemm<32, 32, false><<<L[0].maxchunks, 256, 0, stream>>>(
        g1in, L[0].ei, L[0].u, t7, nullptr, L[0].perm, L[0].ck0, L[0].ccnt, agg, L[0].E);
    spline_node_f<32, 32, NODE_LSM><<<(N1 + 7) / 8, 256, 0, stream>>>(
        g1in, agg, L[0].deg, r7, b7, nullptr, N1, nullptr, nullptr, fc2w, fc2b, out);
}